// Round 6
// baseline (178.818 us; speedup 1.0000x reference)
//
#include <hip/hip_runtime.h>
#include <hip/hip_fp16.h>

typedef unsigned long long u64;
typedef unsigned int uint32;
typedef short short8 __attribute__((ext_vector_type(8)));
typedef float f32x4 __attribute__((ext_vector_type(4)));
typedef _Float16 h2 __attribute__((ext_vector_type(2)));

#define B_N 8192
#define L_N 1024
#define M_N 128
#define C_N 16         // chunks over L
#define CH_N 64        // steps per chunk
#define HALF_N 512

// ws layout (bytes) — proven 35.3MB footprint
#define OFF_W16  0           // w16[i][m] fp16: 256KB
#define OFF_R16  0x40000     // r16[i][m] fp16 (stores r-1): 256KB
#define OFF_BITS 0x80000     // bits[b][16] u64: 1MB
#define OFF_LR   0x180000    // lrT[m][t] bf16: 256KB
#define OFF_RQ   0x1C0000    // Rq[c][b][m] fp16: 32MB
#define OFF_T    0x21C0000   // T[b] int32: 32KB

#define PACK_BLK 2048
#define PACK_IT  16          // 2048*256*16 = B*L
#define EPS_BLK  32
#define ZERO_BLK 32

__device__ __forceinline__ unsigned short f32_bf16(float f) {
    union { float f; unsigned u; } x; x.f = f;
    unsigned u = x.u + 0x7FFFu + ((x.u >> 16) & 1u);   // RNE
    return (unsigned short)(u >> 16);
}

__device__ __forceinline__ float fdot2(h2 a, h2 b, float c) {
#if __has_builtin(__builtin_amdgcn_fdot2)
    return __builtin_amdgcn_fdot2(a, b, c, false);
#else
    return (float)a[0] * (float)b[0] + (float)a[1] * (float)b[1] + c;
#endif
}

__device__ __forceinline__ uint32 fas_u(float f) { union { float f; uint32 u; } x; x.f = f; return x.u; }
__device__ __forceinline__ float uas_f(uint32 u) { union { uint32 u; float f; } x; x.u = u; return x.f; }

// single-instr raw transcendentals (v_exp_f32 / v_log_f32); range proven
// finite by the passing runs of the same formula.
__device__ __forceinline__ float exp2_n(float x) {
#if __has_builtin(__builtin_amdgcn_exp2f)
    return __builtin_amdgcn_exp2f(x);
#else
    return exp2f(x);
#endif
}
__device__ __forceinline__ float log2_n(float x) {
#if __has_builtin(__builtin_amdgcn_logf)
    return __builtin_amdgcn_logf(x);
#else
    return __log2f(x);
#endif
}
// sign-extended single-bit extract: 0 or 0xFFFFFFFF (v_bfe_i32, 1 instr)
__device__ __forceinline__ uint32 bfe1(uint32 v, int off) {
#if __has_builtin(__builtin_amdgcn_sbfe)
    return (uint32)__builtin_amdgcn_sbfe((int)v, off, 1);
#else
    return (uint32)((int)(v << (31 - off)) >> 31);
#endif
}

// x + dpp(y). CTRL: 0xB1 = quad_perm[1,0,3,2] (xor1), 0x4E = quad_perm[2,3,0,1]
// (xor2), 0x104 = row_shl:4 (dest[i]=src[i+4]) — all HW-proven in r3/r4/r5.
// bound_ctrl=1 zero-fills out-of-row lanes; we only consume s<4 results.
template<int CTRL>
__device__ __forceinline__ float dpp_add(float x, float y) {
    union { float f; int i; } a, r;
    a.f = y;
    r.i = __builtin_amdgcn_update_dpp(0, a.i, CTRL, 0xF, 0xF, true);
    return x + r.f;
}

union HU { uint32 u; __half2 hh; h2 v2; };

// ---- K0: fused prep: spin-pack | eps tables (fp16) | zero out -----------
__global__ __launch_bounds__(256) void k_prep(const int* __restrict__ inp,
        const float* __restrict__ eps, u64* __restrict__ bits,
        _Float16* __restrict__ w16, _Float16* __restrict__ r16,
        unsigned short* __restrict__ lrT, float* __restrict__ out) {
    int bid = blockIdx.x;
    if (bid < PACK_BLK) {
        int g = bid * 256 + threadIdx.x;
        const int stride = PACK_BLK * 256;
        #pragma unroll 4
        for (int it = 0; it < PACK_IT; ++it) {
            int v = inp[g];
            u64 m = __ballot(v != 0);
            if ((threadIdx.x & 63) == 0) bits[g >> 6] = m;
            g += stride;
        }
        return;
    }
    bid -= PACK_BLK;
    if (bid < EPS_BLK) {
        int wid = threadIdx.x >> 6, lane = threadIdx.x & 63;
        int m = bid * 4 + wid;
        const float* e0 = eps + (size_t)m * L_N + lane * 16;
        const float* e1 = eps + (size_t)(M_N + m) * L_N + lane * 16;
        float a[16], b[16];
        #pragma unroll
        for (int j = 0; j < 16; j += 4) {
            *(float4*)&a[j] = *(const float4*)&e0[j];
            *(float4*)&b[j] = *(const float4*)&e1[j];
        }
        float local = 1.f;
        #pragma unroll
        for (int j = 0; j < 16; ++j) local *= a[j];
        float sc = local;
        #pragma unroll
        for (int d = 1; d < 64; d <<= 1) {
            float up = __shfl_up(sc, d);
            if (lane >= d) sc *= up;
        }
        float prev = __shfl_up(sc, 1);
        float E = (lane == 0) ? 1.f : prev;
        int i0 = lane * 16;
        #pragma unroll
        for (int j = 0; j < 16; ++j) {
            float rat = b[j] / a[j];
            w16[(size_t)(i0 + j) * M_N + m] = (_Float16)(E * (a[j] - b[j]));
            r16[(size_t)(i0 + j) * M_N + m] = (_Float16)(rat - 1.f);   // r-1 for pk_fma
            lrT[(size_t)m * L_N + i0 + j] = f32_bf16(__log2f(rat));
            E *= a[j];
        }
        return;
    }
    bid -= EPS_BLK;
    if (bid < ZERO_BLK) {
        out[bid * 256 + threadIdx.x] = 0.f;
    }
}

// ---- K2: MFMA chunk log-sums + f32 cumsum + exp2 -> fp16 excl prefix ----
// blocks [0,1024): prefix; blocks [1024,1056): per-b saturation step T.
__global__ __launch_bounds__(256) void k_slog2(const u64* __restrict__ bits,
        const unsigned short* __restrict__ lrT, _Float16* __restrict__ Rq,
        int* __restrict__ T) {
    if (blockIdx.x >= 1024) {
        int b = (blockIdx.x - 1024) * 256 + threadIdx.x;
        const u64* brow = bits + (size_t)b * 16;
        int n1 = 0, n0 = 0, Tv = 1024;
        for (int wd = 0; wd < 16; ++wd) {
            u64 x = brow[wd];
            int pc = __popcll(x);
            if (n1 + pc < HALF_N && n0 + (64 - pc) < HALF_N) {
                n1 += pc; n0 += 64 - pc;
                continue;
            }
            int found = 0;
            for (int k = 0; k < 64; ++k) {
                if (n1 >= HALF_N || n0 >= HALF_N) { Tv = wd * 64 + k; found = 1; break; }
                int sb = (int)((x >> k) & 1);
                n1 += sb; n0 += 1 - sb;
            }
            if (!found) Tv = (wd + 1) * 64;
            break;
        }
        T[b] = Tv;
        return;
    }
    int btile = blockIdx.x >> 1;
    int half = blockIdx.x & 1;
    int wid = threadIdx.x >> 6, lane = threadIdx.x & 63;
    int col = lane & 15, quad = lane >> 4;
    int m = (half * 4 + wid) * 16 + col;
    int b_row = btile * 16 + col;
    const u64* brow = bits + (size_t)b_row * 16;
    const unsigned short* lrow = lrT + (size_t)m * L_N;

    f32x4 cum = (f32x4){0.f, 0.f, 0.f, 0.f};

    for (int c = 0; c < C_N; ++c) {
        #pragma unroll
        for (int reg = 0; reg < 4; ++reg) {
            int b = btile * 16 + quad * 4 + reg;
            Rq[((size_t)c * B_N + b) * M_N + m] = (_Float16)exp2_n(cum[reg]);
        }
        u64 wv = brow[c];
        short8 a0, a1;
        #pragma unroll
        for (int j = 0; j < 8; ++j) {
            a0[j] = (short)((((wv >> (quad * 8 + j)) & 1) != 0) ? 0x3F80 : 0);
            a1[j] = (short)((((wv >> (32 + quad * 8 + j)) & 1) != 0) ? 0x3F80 : 0);
        }
        const unsigned short* bp = lrow + c * 64 + quad * 8;
        union { uint4 u; short8 s; } bf0, bf1;
        bf0.u = *(const uint4*)bp;
        bf1.u = *(const uint4*)(bp + 32);
        cum = __builtin_amdgcn_mfma_f32_16x16x32_bf16(a0, bf0.s, cum, 0, 0, 0);
        cum = __builtin_amdgcn_mfma_f32_16x16x32_bf16(a1, bf1.s, cum, 0, 0, 0);
    }
}

// ------- K3: main loop — 8 b's per 8-lane group (halved LDS bytes/bm) ----
// Lane s (0..7) owns m-slice s*16..s*16+15; R2[k] = running product for
// b0+(s^k), k=0..7. One 64B W+Rm read per step now serves 8 b's (0.5 B/bm,
// was 1.0). Butterfly: xor1, xor2 quad-perms, then row_shl:4 twice gives
// both D_lo (b0+s) and D_hi (b0+4+s) on lanes s<4.
__global__ __launch_bounds__(128) void k_main(const u64* __restrict__ bits,
        const _Float16* __restrict__ w16, const _Float16* __restrict__ r16,
        const _Float16* __restrict__ Rq, const int* __restrict__ T,
        float* __restrict__ out) {
    __shared__ _Float16 wbuf[CH_N * M_N];   // 16KB
    __shared__ _Float16 rbuf[CH_N * M_N];   // 16KB
    int c = blockIdx.x & (C_N - 1);
    int bblk = blockIdx.x >> 4;
    int lane = threadIdx.x & 63, wid = threadIdx.x >> 6;
    int s = lane & 7, grp = lane >> 3;
    int b0 = bblk * 128 + wid * 64 + grp * 8;

    // stage full chunk (16KB per table, coalesced uint4; 128 threads x 8)
    {
        const uint4* sw = (const uint4*)(w16 + (size_t)c * CH_N * M_N);
        const uint4* sr = (const uint4*)(r16 + (size_t)c * CH_N * M_N);
        uint4* dw = (uint4*)wbuf; uint4* dr = (uint4*)rbuf;
        #pragma unroll
        for (int t = 0; t < 8; ++t) {
            dw[threadIdx.x + t * 128] = sw[threadIdx.x + t * 128];
            dr[threadIdx.x + t * 128] = sr[threadIdx.x + t * 128];
        }
    }

    // prefix load: R2[k][j] = packed pair for b0+(s^k), m = s*16+2j
    HU R2[8][8];
    u64 wb[8];
    #pragma unroll
    for (int k = 0; k < 8; ++k) {
        int b = b0 + (s ^ k);
        union { uint4 v[2]; uint32 w[8]; } P;
        const uint4* src = (const uint4*)(Rq + ((size_t)c * B_N + b) * M_N + s * 16);
        P.v[0] = src[0]; P.v[1] = src[1];
        #pragma unroll
        for (int j = 0; j < 8; ++j) R2[k][j].u = P.w[j];
        wb[k] = bits[(size_t)b * 16 + c];
    }
    int Tb_lo = T[b0 + (s & 3)];
    int Tb_hi = T[b0 + 4 + (s & 3)];

    __syncthreads();

    const float LOG2E2 = 2.885390082f; // 2*log2(e)
    const float NHL2 = -0.3465735903f; // -0.5*ln2
    float sum_lo = 0.f, sum_hi = 0.f;
    #pragma unroll
    for (int h = 0; h < 2; ++h) {
        uint32 wh[8];
        #pragma unroll
        for (int k = 0; k < 8; ++k) wh[k] = (uint32)(wb[k] >> (h * 32));
        uint32 ows_lo = ~wh[0];               // sign word for b0+s   (k=0)
        uint32 ows_hi = ~wh[4];               // sign word for b0+4+s (k=4)
        int rel_lo = Tb_lo - (c * CH_N + h * 32);
        int rel_hi = Tb_hi - (c * CH_N + h * 32);
        uint32 vm_lo = (rel_lo <= 0) ? 0u : ((rel_lo >= 32) ? 0xFFFFFFFFu : ((1u << rel_lo) - 1u));
        uint32 vm_hi = (rel_hi <= 0) ? 0u : ((rel_hi >= 32) ? 0xFFFFFFFFu : ((1u << rel_hi) - 1u));

        #pragma unroll 2
        for (int tt = 0; tt < 32; ++tt) {
            int base = (h * 32 + tt) * M_N + s * 16;
            union { uint4 q4[2]; uint32 w[8]; h2 v2[8]; } W, Rm;
            W.q4[0] = *(const uint4*)&wbuf[base];
            W.q4[1] = *((const uint4*)&wbuf[base] + 1);
            Rm.q4[0] = *(const uint4*)&rbuf[base];
            Rm.q4[1] = *((const uint4*)&rbuf[base] + 1);

            float d[8];
            #pragma unroll
            for (int k = 0; k < 8; ++k) {
                float acc = 0.f;
                #pragma unroll
                for (int j = 0; j < 8; ++j) acc = fdot2(R2[k][j].v2, W.v2[j], acc);
                d[k] = acc;
            }
            // butterfly: stage0 xor1 (partner's d[k^1] is our b), stage1 xor2,
            // stage2 row_shl:4 twice -> D_lo (b0+s) and D_hi (b0+4+s) on s<4
            float a0 = dpp_add<0xB1>(d[0], d[1]);
            float a2 = dpp_add<0xB1>(d[2], d[3]);
            float a4 = dpp_add<0xB1>(d[4], d[5]);
            float a6 = dpp_add<0xB1>(d[6], d[7]);
            float u0 = dpp_add<0x4E>(a0, a2);
            float u4 = dpp_add<0x4E>(a4, a6);
            float D_lo = dpp_add<0x104>(u0, u4);   // A0 + shl4(A4)
            float D_hi = dpp_add<0x104>(u4, u0);   // A4 + shl4(A0)

            // softplus x2: -0.5*ln2 * log2(1 + 2^(2*log2e*y)), y = +-D
            uint32 sg_lo = bfe1(ows_lo, tt) & 0x80000000u;
            float y_lo = uas_f(fas_u(D_lo) ^ sg_lo);
            float ct_lo = NHL2 * log2_n(1.f + exp2_n(LOG2E2 * y_lo));
            sum_lo += uas_f(fas_u(ct_lo) & bfe1(vm_lo, tt));
            uint32 sg_hi = bfe1(ows_hi, tt) & 0x80000000u;
            float y_hi = uas_f(fas_u(D_hi) ^ sg_hi);
            float ct_hi = NHL2 * log2_n(1.f + exp2_n(LOG2E2 * y_hi));
            sum_hi += uas_f(fas_u(ct_hi) & bfe1(vm_hi, tt));

            // update: R2 *= (1 + (r-1)&mask)  (bfe mask + AND + packed fma)
            #pragma unroll
            for (int k = 0; k < 8; ++k) {
                uint32 msk = bfe1(wh[k], tt);
                #pragma unroll
                for (int j = 0; j < 8; ++j) {
                    HU sel; sel.u = Rm.w[j] & msk;
                    R2[k][j].hh = __hfma2(sel.hh, R2[k][j].hh, R2[k][j].hh);
                }
            }
        }
    }
    if (s < 4) {
        atomicAdd(&out[b0 + s], sum_lo);
        atomicAdd(&out[b0 + 4 + s], sum_hi);
    }
}

extern "C" void kernel_launch(void* const* d_in, const int* in_sizes, int n_in,
                              void* d_out, int out_size, void* d_ws, size_t ws_size,
                              hipStream_t stream) {
    const int*   inputs  = (const int*)d_in[0];     // (B, L) int32
    const float* epsilon = (const float*)d_in[1];   // (D, M, L) f32
    float* out = (float*)d_out;                     // (B,) f32

    char* ws = (char*)d_ws;
    _Float16* w16 = (_Float16*)(ws + OFF_W16);
    _Float16* r16 = (_Float16*)(ws + OFF_R16);
    u64*   bits   = (u64*)  (ws + OFF_BITS);
    unsigned short* lrT = (unsigned short*)(ws + OFF_LR);
    _Float16* Rq  = (_Float16*)(ws + OFF_RQ);
    int*   T      = (int*)  (ws + OFF_T);

    k_prep<<<PACK_BLK + EPS_BLK + ZERO_BLK, 256, 0, stream>>>(
        inputs, epsilon, bits, w16, r16, lrT, out);
    k_slog2<<<1024 + 32, 256, 0, stream>>>(bits, lrT, Rq, T);
    k_main<<<(B_N / 128) * C_N, 128, 0, stream>>>(bits, w16, r16, Rq, T, out);
}

// Round 7
// 172.029 us; speedup vs baseline: 1.0395x; 1.0395x over previous
//
#include <hip/hip_runtime.h>
#include <hip/hip_fp16.h>

typedef unsigned long long u64;
typedef unsigned int uint32;
typedef short short8 __attribute__((ext_vector_type(8)));
typedef float f32x4 __attribute__((ext_vector_type(4)));
typedef _Float16 h2 __attribute__((ext_vector_type(2)));

#define B_N 8192
#define L_N 1024
#define M_N 128
#define HALF_N 512

// ws layout (bytes). T moved before Rq so Rq can grow.
#define OFF_W16  0           // w16[i][m] fp16: 256KB
#define OFF_R16  0x40000     // r16[i][m] fp16 (stores r-1): 256KB
#define OFF_BITS 0x80000     // bits[b][16] u64: 1MB
#define OFF_LR   0x180000    // lrT[m][t] bf16: 256KB
#define OFF_T    0x1C0000    // T[b] int32: 32KB
#define OFF_RQ   0x200000    // Rq[cn][b][m] fp16: 32MB (cn=16) or 64MB (cn=32)

#define PACK_BLK 2048
#define PACK_IT  16          // 2048*256*16 = B*L
#define EPS_BLK  32
#define ZERO_BLK 32

__device__ __forceinline__ unsigned short f32_bf16(float f) {
    union { float f; unsigned u; } x; x.f = f;
    unsigned u = x.u + 0x7FFFu + ((x.u >> 16) & 1u);   // RNE
    return (unsigned short)(u >> 16);
}

__device__ __forceinline__ float fdot2(h2 a, h2 b, float c) {
#if __has_builtin(__builtin_amdgcn_fdot2)
    return __builtin_amdgcn_fdot2(a, b, c, false);
#else
    return (float)a[0] * (float)b[0] + (float)a[1] * (float)b[1] + c;
#endif
}

__device__ __forceinline__ uint32 fas_u(float f) { union { float f; uint32 u; } x; x.f = f; return x.u; }
__device__ __forceinline__ float uas_f(uint32 u) { union { uint32 u; float f; } x; x.u = u; return x.f; }

// single-instr raw transcendentals (v_exp_f32 / v_log_f32); range proven
// finite by the passing runs of the same formula.
__device__ __forceinline__ float exp2_n(float x) {
#if __has_builtin(__builtin_amdgcn_exp2f)
    return __builtin_amdgcn_exp2f(x);
#else
    return exp2f(x);
#endif
}
__device__ __forceinline__ float log2_n(float x) {
#if __has_builtin(__builtin_amdgcn_logf)
    return __builtin_amdgcn_logf(x);
#else
    return __log2f(x);
#endif
}
// sign-extended single-bit extract: 0 or 0xFFFFFFFF (v_bfe_i32, 1 instr)
__device__ __forceinline__ uint32 bfe1(uint32 v, int off) {
#if __has_builtin(__builtin_amdgcn_sbfe)
    return (uint32)__builtin_amdgcn_sbfe((int)v, off, 1);
#else
    return (uint32)((int)(v << (31 - off)) >> 31);
#endif
}

// x + dpp(y). CTRL: 0xB1 = quad_perm[1,0,3,2] (xor1), 0x4E = quad_perm[2,3,0,1]
// (xor2), 0x104 = row_shl:4 (dest[i]=src[i+4]) — all HW-proven in r3/r4/r5.
template<int CTRL>
__device__ __forceinline__ float dpp_add(float x, float y) {
    union { float f; int i; } a, r;
    a.f = y;
    r.i = __builtin_amdgcn_update_dpp(0, a.i, CTRL, 0xF, 0xF, true);
    return x + r.f;
}

union HU { uint32 u; __half2 hh; h2 v2; };

// ---- K0: fused prep: spin-pack | eps tables (fp16) | zero out -----------
__global__ __launch_bounds__(256) void k_prep(const int* __restrict__ inp,
        const float* __restrict__ eps, u64* __restrict__ bits,
        _Float16* __restrict__ w16, _Float16* __restrict__ r16,
        unsigned short* __restrict__ lrT, float* __restrict__ out) {
    int bid = blockIdx.x;
    if (bid < PACK_BLK) {
        int g = bid * 256 + threadIdx.x;
        const int stride = PACK_BLK * 256;
        #pragma unroll 4
        for (int it = 0; it < PACK_IT; ++it) {
            int v = inp[g];
            u64 m = __ballot(v != 0);
            if ((threadIdx.x & 63) == 0) bits[g >> 6] = m;
            g += stride;
        }
        return;
    }
    bid -= PACK_BLK;
    if (bid < EPS_BLK) {
        int wid = threadIdx.x >> 6, lane = threadIdx.x & 63;
        int m = bid * 4 + wid;
        const float* e0 = eps + (size_t)m * L_N + lane * 16;
        const float* e1 = eps + (size_t)(M_N + m) * L_N + lane * 16;
        float a[16], b[16];
        #pragma unroll
        for (int j = 0; j < 16; j += 4) {
            *(float4*)&a[j] = *(const float4*)&e0[j];
            *(float4*)&b[j] = *(const float4*)&e1[j];
        }
        float local = 1.f;
        #pragma unroll
        for (int j = 0; j < 16; ++j) local *= a[j];
        float sc = local;
        #pragma unroll
        for (int d = 1; d < 64; d <<= 1) {
            float up = __shfl_up(sc, d);
            if (lane >= d) sc *= up;
        }
        float prev = __shfl_up(sc, 1);
        float E = (lane == 0) ? 1.f : prev;
        int i0 = lane * 16;
        #pragma unroll
        for (int j = 0; j < 16; ++j) {
            float rat = b[j] / a[j];
            w16[(size_t)(i0 + j) * M_N + m] = (_Float16)(E * (a[j] - b[j]));
            r16[(size_t)(i0 + j) * M_N + m] = (_Float16)(rat - 1.f);   // r-1 for pk_fma
            lrT[(size_t)m * L_N + i0 + j] = f32_bf16(__log2f(rat));
            E *= a[j];
        }
        return;
    }
    bid -= EPS_BLK;
    if (bid < ZERO_BLK) {
        out[bid * 256 + threadIdx.x] = 0.f;
    }
}

// ---- K2: MFMA chunk log-sums + f32 cumsum + exp2 -> fp16 excl prefix ----
// blocks [0,1024): prefix at CN granularity; [1024,1056): saturation T.
template<int CN>
__global__ __launch_bounds__(256) void k_slog2(const u64* __restrict__ bits,
        const unsigned short* __restrict__ lrT, _Float16* __restrict__ Rq,
        int* __restrict__ T) {
    if (blockIdx.x >= 1024) {
        int b = (blockIdx.x - 1024) * 256 + threadIdx.x;
        const u64* brow = bits + (size_t)b * 16;
        int n1 = 0, n0 = 0, Tv = 1024;
        for (int wd = 0; wd < 16; ++wd) {
            u64 x = brow[wd];
            int pc = __popcll(x);
            if (n1 + pc < HALF_N && n0 + (64 - pc) < HALF_N) {
                n1 += pc; n0 += 64 - pc;
                continue;
            }
            int found = 0;
            for (int k = 0; k < 64; ++k) {
                if (n1 >= HALF_N || n0 >= HALF_N) { Tv = wd * 64 + k; found = 1; break; }
                int sb = (int)((x >> k) & 1);
                n1 += sb; n0 += 1 - sb;
            }
            if (!found) Tv = (wd + 1) * 64;
            break;
        }
        T[b] = Tv;
        return;
    }
    int btile = blockIdx.x >> 1;
    int half = blockIdx.x & 1;
    int wid = threadIdx.x >> 6, lane = threadIdx.x & 63;
    int col = lane & 15, quad = lane >> 4;
    int m = (half * 4 + wid) * 16 + col;
    int b_row = btile * 16 + col;
    const u64* brow = bits + (size_t)b_row * 16;
    const unsigned short* lrow = lrT + (size_t)m * L_N;

    f32x4 cum = (f32x4){0.f, 0.f, 0.f, 0.f};

    for (int w = 0; w < 16; ++w) {
        u64 wv = brow[w];
        #pragma unroll
        for (int hf = 0; hf < 2; ++hf) {
            if (CN == 32 || hf == 0) {
                int cc = (CN == 32) ? (w * 2 + hf) : w;
                #pragma unroll
                for (int reg = 0; reg < 4; ++reg) {
                    int b = btile * 16 + quad * 4 + reg;
                    Rq[((size_t)cc * B_N + b) * M_N + m] = (_Float16)exp2_n(cum[reg]);
                }
            }
            short8 a;
            #pragma unroll
            for (int j = 0; j < 8; ++j)
                a[j] = (short)((((wv >> (hf * 32 + quad * 8 + j)) & 1) != 0) ? 0x3F80 : 0);
            union { uint4 u; short8 s; } bf;
            bf.u = *(const uint4*)(lrow + w * 64 + hf * 32 + quad * 8);
            cum = __builtin_amdgcn_mfma_f32_16x16x32_bf16(a, bf.s, cum, 0, 0, 0);
        }
    }
}

// ------- K3: main loop — R5-proven body, templated chunk count ----------
// 8 lanes (s=0..7) handle 4 b's x 128 m's; lane s owns m-slice s*16..s*16+15;
// R2[k] = running product for b0 + ((s&3)^k): k-permute makes the butterfly
// select-free (each stage's DPP partner holds OUR b's partial).
template<int CN>
__global__ __launch_bounds__(256, 2) void k_main(const u64* __restrict__ bits,
        const _Float16* __restrict__ w16, const _Float16* __restrict__ r16,
        const _Float16* __restrict__ Rq, const int* __restrict__ T,
        float* __restrict__ out) {
    constexpr int CHN = L_N / CN;                // 64 or 32 steps per chunk
    constexpr int CSH = (CN == 16) ? 4 : 5;
    constexpr int NV  = (CHN * M_N) / (8 * 256); // uint4 per thread per table
    __shared__ _Float16 wbuf[CHN * M_N];         // 16KB or 8KB
    __shared__ _Float16 rbuf[CHN * M_N];
    int c = blockIdx.x & (CN - 1);
    int bblk = blockIdx.x >> CSH;
    int lane = threadIdx.x & 63, wid = threadIdx.x >> 6;
    int s = lane & 7, grp = lane >> 3;
    int q = s & 3;
    int b0 = bblk * 128 + wid * 32 + grp * 4;

    // stage chunk tables (coalesced uint4)
    {
        const uint4* sw = (const uint4*)(w16 + (size_t)c * CHN * M_N);
        const uint4* sr = (const uint4*)(r16 + (size_t)c * CHN * M_N);
        uint4* dw = (uint4*)wbuf; uint4* dr = (uint4*)rbuf;
        #pragma unroll
        for (int t = 0; t < NV; ++t) {
            dw[threadIdx.x + t * 256] = sw[threadIdx.x + t * 256];
            dr[threadIdx.x + t * 256] = sr[threadIdx.x + t * 256];
        }
    }

    // prefix load: R2[k][j] = packed pair for b0+(q^k), m = s*16+2j
    HU R2[4][8];
    u64 wb[4];
    const int word0 = (c * CHN) >> 6;            // u64 word holding this chunk
    const int hs0 = (c * CHN >> 5) & 1;          // starting 32-bit half
    #pragma unroll
    for (int k = 0; k < 4; ++k) {
        int b = b0 + (q ^ k);
        union { uint4 v[2]; uint32 w[8]; } P;
        const uint4* src = (const uint4*)(Rq + ((size_t)c * B_N + b) * M_N + s * 16);
        P.v[0] = src[0]; P.v[1] = src[1];
        #pragma unroll
        for (int j = 0; j < 8; ++j) R2[k][j].u = P.w[j];
        wb[k] = bits[(size_t)b * 16 + word0];
    }
    int Tb = T[b0 + q];

    __syncthreads();

    const float LOG2E2 = 2.885390082f; // 2*log2(e)
    const float NHL2 = -0.3465735903f; // -0.5*ln2
    float sum = 0.f;
    #pragma unroll
    for (int h = 0; h < CHN / 32; ++h) {
        int sh = ((hs0 + h) & 1) * 32;
        uint32 wh[4];
        #pragma unroll
        for (int k = 0; k < 4; ++k) wh[k] = (uint32)(wb[k] >> sh);
        uint32 ows = ~wh[0];                   // own b's word; bit==0 -> flip sign
        int rel = Tb - (c * CHN + h * 32);
        uint32 vmask = (rel <= 0) ? 0u : ((rel >= 32) ? 0xFFFFFFFFu : ((1u << rel) - 1u));

        for (int tt = 0; tt < 32; ++tt) {
            int base = (h * 32 + tt) * M_N + s * 16;
            union { uint4 q4[2]; uint32 w[8]; h2 v2[8]; } W, Rm;
            W.q4[0] = *(const uint4*)&wbuf[base];
            W.q4[1] = *((const uint4*)&wbuf[base] + 1);
            Rm.q4[0] = *(const uint4*)&rbuf[base];
            Rm.q4[1] = *((const uint4*)&rbuf[base] + 1);

            float d[4];
            #pragma unroll
            for (int k = 0; k < 4; ++k) {
                float acc = 0.f;
                #pragma unroll
                for (int j = 0; j < 8; ++j) acc = fdot2(R2[k][j].v2, W.v2[j], acc);
                d[k] = acc;
            }
            // select-free butterfly: each stage's partner holds OUR b's partial
            float xa = dpp_add<0xB1>(d[0], d[1]);   // + lane s^1 (its d[1] = our b)
            float xb = dpp_add<0xB1>(d[2], d[3]);   // partial for b^2
            float uD = dpp_add<0x4E>(xa, xb);       // + lane s^2 (its xb = our b)
            uD = dpp_add<0x104>(uD, uD);            // + lane s+4 (row_shl:4)

            // softplus: -0.5*ln2 * log2(1 + 2^(2*log2e*y)), y = +-D by sign-xor
            uint32 sgn = bfe1(ows, tt) & 0x80000000u;
            float y = uas_f(fas_u(uD) ^ sgn);
            float contr = NHL2 * log2_n(1.f + exp2_n(LOG2E2 * y));
            sum += uas_f(fas_u(contr) & bfe1(vmask, tt));

            // update: R2 *= (1 + (r-1)&mask)  (bfe mask + AND + packed fma)
            #pragma unroll
            for (int k = 0; k < 4; ++k) {
                uint32 msk = bfe1(wh[k], tt);
                #pragma unroll
                for (int j = 0; j < 8; ++j) {
                    HU sel; sel.u = Rm.w[j] & msk;
                    R2[k][j].v2 += sel.v2 * R2[k][j].v2;
                }
            }
        }
    }
    if (s < 4) atomicAdd(&out[b0 + s], sum);
}

extern "C" void kernel_launch(void* const* d_in, const int* in_sizes, int n_in,
                              void* d_out, int out_size, void* d_ws, size_t ws_size,
                              hipStream_t stream) {
    const int*   inputs  = (const int*)d_in[0];     // (B, L) int32
    const float* epsilon = (const float*)d_in[1];   // (D, M, L) f32
    float* out = (float*)d_out;                     // (B,) f32

    char* ws = (char*)d_ws;
    _Float16* w16 = (_Float16*)(ws + OFF_W16);
    _Float16* r16 = (_Float16*)(ws + OFF_R16);
    u64*   bits   = (u64*)  (ws + OFF_BITS);
    unsigned short* lrT = (unsigned short*)(ws + OFF_LR);
    int*   T      = (int*)  (ws + OFF_T);
    _Float16* Rq  = (_Float16*)(ws + OFF_RQ);

    k_prep<<<PACK_BLK + EPS_BLK + ZERO_BLK, 256, 0, stream>>>(
        inputs, epsilon, bits, w16, r16, lrT, out);

    // CN=32 needs 64MB Rq (high-water ~69MB); fall back to proven CN=16 if
    // the workspace can't hold it.
    const size_t need32 = (size_t)OFF_RQ + (size_t)32 * B_N * M_N * 2;
    if (ws_size >= need32) {
        k_slog2<32><<<1024 + 32, 256, 0, stream>>>(bits, lrT, Rq, T);
        k_main<32><<<(B_N / 128) * 32, 256, 0, stream>>>(bits, w16, r16, Rq, T, out);
    } else {
        k_slog2<16><<<1024 + 32, 256, 0, stream>>>(bits, lrT, Rq, T);
        k_main<16><<<(B_N / 128) * 16, 256, 0, stream>>>(bits, w16, r16, Rq, T, out);
    }
}

// Round 8
// 171.801 us; speedup vs baseline: 1.0408x; 1.0013x over previous
//
#include <hip/hip_runtime.h>
#include <hip/hip_fp16.h>

typedef unsigned long long u64;
typedef unsigned int uint32;
typedef short short8 __attribute__((ext_vector_type(8)));
typedef float f32x4 __attribute__((ext_vector_type(4)));
typedef _Float16 h2 __attribute__((ext_vector_type(2)));

#define B_N 8192
#define L_N 1024
#define M_N 128
#define HALF_N 512

// ws layout (bytes). T moved before Rq so Rq can grow.
#define OFF_W16  0           // w16[i][m] fp16: 256KB
#define OFF_R16  0x40000     // r16[i][m] fp16 (stores r-1): 256KB
#define OFF_BITS 0x80000     // bits[b][16] u64: 1MB
#define OFF_LR   0x180000    // lrT[m][t] bf16: 256KB
#define OFF_T    0x1C0000    // T[b] int32: 32KB
#define OFF_RQ   0x200000    // Rq[cn][b][m] fp16: 32MB (cn=16) or 64MB (cn=32)

#define PACK_BLK 2048
#define PACK_IT  16          // 2048*256*16 = B*L
#define EPS_BLK  32
#define ZERO_BLK 32

__device__ __forceinline__ unsigned short f32_bf16(float f) {
    union { float f; unsigned u; } x; x.f = f;
    unsigned u = x.u + 0x7FFFu + ((x.u >> 16) & 1u);   // RNE
    return (unsigned short)(u >> 16);
}

__device__ __forceinline__ float fdot2(h2 a, h2 b, float c) {
#if __has_builtin(__builtin_amdgcn_fdot2)
    return __builtin_amdgcn_fdot2(a, b, c, false);
#else
    return (float)a[0] * (float)b[0] + (float)a[1] * (float)b[1] + c;
#endif
}

__device__ __forceinline__ uint32 fas_u(float f) { union { float f; uint32 u; } x; x.f = f; return x.u; }
__device__ __forceinline__ float uas_f(uint32 u) { union { uint32 u; float f; } x; x.u = u; return x.f; }

// single-instr raw transcendentals (v_exp_f32 / v_log_f32); range proven
// finite by the passing runs of the same formula.
__device__ __forceinline__ float exp2_n(float x) {
#if __has_builtin(__builtin_amdgcn_exp2f)
    return __builtin_amdgcn_exp2f(x);
#else
    return exp2f(x);
#endif
}
__device__ __forceinline__ float log2_n(float x) {
#if __has_builtin(__builtin_amdgcn_logf)
    return __builtin_amdgcn_logf(x);
#else
    return __log2f(x);
#endif
}
// sign-extended single-bit extract: 0 or 0xFFFFFFFF (v_bfe_i32, 1 instr)
__device__ __forceinline__ uint32 bfe1(uint32 v, int off) {
#if __has_builtin(__builtin_amdgcn_sbfe)
    return (uint32)__builtin_amdgcn_sbfe((int)v, off, 1);
#else
    return (uint32)((int)(v << (31 - off)) >> 31);
#endif
}

// x + dpp(y). CTRL: 0xB1 = quad_perm[1,0,3,2] (xor1), 0x4E = quad_perm[2,3,0,1]
// (xor2), 0x104 = row_shl:4 (dest[i]=src[i+4]) — all HW-proven in r3/r4/r5.
template<int CTRL>
__device__ __forceinline__ float dpp_add(float x, float y) {
    union { float f; int i; } a, r;
    a.f = y;
    r.i = __builtin_amdgcn_update_dpp(0, a.i, CTRL, 0xF, 0xF, true);
    return x + r.f;
}

union HU { uint32 u; __half2 hh; h2 v2; };

// ---- K0: fused prep: spin-pack | eps tables (fp16) | zero out -----------
__global__ __launch_bounds__(256) void k_prep(const int* __restrict__ inp,
        const float* __restrict__ eps, u64* __restrict__ bits,
        _Float16* __restrict__ w16, _Float16* __restrict__ r16,
        unsigned short* __restrict__ lrT, float* __restrict__ out) {
    int bid = blockIdx.x;
    if (bid < PACK_BLK) {
        int g = bid * 256 + threadIdx.x;
        const int stride = PACK_BLK * 256;
        #pragma unroll 4
        for (int it = 0; it < PACK_IT; ++it) {
            int v = inp[g];
            u64 m = __ballot(v != 0);
            if ((threadIdx.x & 63) == 0) bits[g >> 6] = m;
            g += stride;
        }
        return;
    }
    bid -= PACK_BLK;
    if (bid < EPS_BLK) {
        int wid = threadIdx.x >> 6, lane = threadIdx.x & 63;
        int m = bid * 4 + wid;
        const float* e0 = eps + (size_t)m * L_N + lane * 16;
        const float* e1 = eps + (size_t)(M_N + m) * L_N + lane * 16;
        float a[16], b[16];
        #pragma unroll
        for (int j = 0; j < 16; j += 4) {
            *(float4*)&a[j] = *(const float4*)&e0[j];
            *(float4*)&b[j] = *(const float4*)&e1[j];
        }
        float local = 1.f;
        #pragma unroll
        for (int j = 0; j < 16; ++j) local *= a[j];
        float sc = local;
        #pragma unroll
        for (int d = 1; d < 64; d <<= 1) {
            float up = __shfl_up(sc, d);
            if (lane >= d) sc *= up;
        }
        float prev = __shfl_up(sc, 1);
        float E = (lane == 0) ? 1.f : prev;
        int i0 = lane * 16;
        #pragma unroll
        for (int j = 0; j < 16; ++j) {
            float rat = b[j] / a[j];
            w16[(size_t)(i0 + j) * M_N + m] = (_Float16)(E * (a[j] - b[j]));
            r16[(size_t)(i0 + j) * M_N + m] = (_Float16)(rat - 1.f);   // r-1 for pk_fma
            lrT[(size_t)m * L_N + i0 + j] = f32_bf16(__log2f(rat));
            E *= a[j];
        }
        return;
    }
    bid -= EPS_BLK;
    if (bid < ZERO_BLK) {
        out[bid * 256 + threadIdx.x] = 0.f;
    }
}

// ---- K2: MFMA chunk log-sums + f32 cumsum + exp2 -> fp16 excl prefix ----
// blocks [0,1024): prefix at CN granularity; [1024,1056): saturation T.
template<int CN>
__global__ __launch_bounds__(256) void k_slog2(const u64* __restrict__ bits,
        const unsigned short* __restrict__ lrT, _Float16* __restrict__ Rq,
        int* __restrict__ T) {
    if (blockIdx.x >= 1024) {
        int b = (blockIdx.x - 1024) * 256 + threadIdx.x;
        const u64* brow = bits + (size_t)b * 16;
        int n1 = 0, n0 = 0, Tv = 1024;
        for (int wd = 0; wd < 16; ++wd) {
            u64 x = brow[wd];
            int pc = __popcll(x);
            if (n1 + pc < HALF_N && n0 + (64 - pc) < HALF_N) {
                n1 += pc; n0 += 64 - pc;
                continue;
            }
            int found = 0;
            for (int k = 0; k < 64; ++k) {
                if (n1 >= HALF_N || n0 >= HALF_N) { Tv = wd * 64 + k; found = 1; break; }
                int sb = (int)((x >> k) & 1);
                n1 += sb; n0 += 1 - sb;
            }
            if (!found) Tv = (wd + 1) * 64;
            break;
        }
        T[b] = Tv;
        return;
    }
    int btile = blockIdx.x >> 1;
    int half = blockIdx.x & 1;
    int wid = threadIdx.x >> 6, lane = threadIdx.x & 63;
    int col = lane & 15, quad = lane >> 4;
    int m = (half * 4 + wid) * 16 + col;
    int b_row = btile * 16 + col;
    const u64* brow = bits + (size_t)b_row * 16;
    const unsigned short* lrow = lrT + (size_t)m * L_N;

    f32x4 cum = (f32x4){0.f, 0.f, 0.f, 0.f};

    for (int w = 0; w < 16; ++w) {
        u64 wv = brow[w];
        #pragma unroll
        for (int hf = 0; hf < 2; ++hf) {
            if (CN == 32 || hf == 0) {
                int cc = (CN == 32) ? (w * 2 + hf) : w;
                #pragma unroll
                for (int reg = 0; reg < 4; ++reg) {
                    int b = btile * 16 + quad * 4 + reg;
                    Rq[((size_t)cc * B_N + b) * M_N + m] = (_Float16)exp2_n(cum[reg]);
                }
            }
            short8 a;
            #pragma unroll
            for (int j = 0; j < 8; ++j)
                a[j] = (short)((((wv >> (hf * 32 + quad * 8 + j)) & 1) != 0) ? 0x3F80 : 0);
            union { uint4 u; short8 s; } bf;
            bf.u = *(const uint4*)(lrow + w * 64 + hf * 32 + quad * 8);
            cum = __builtin_amdgcn_mfma_f32_16x16x32_bf16(a, bf.s, cum, 0, 0, 0);
        }
    }
}

// ------- K3: main loop — R7 body, register-pressure fix -----------------
// amdgpu_waves_per_eu(1,4): stop the allocator from capping arch VGPRs at
// 32-48 (occupancy heuristic) and shuffling R2/W/Rm through AGPRs with
// v_accvgpr_read/write — the ~2x VALU instruction inflation seen in PMC
// (240 instrs/wave-step measured vs ~126 architectural).
template<int CN>
__global__ __launch_bounds__(256) __attribute__((amdgpu_waves_per_eu(1, 4)))
void k_main(const u64* __restrict__ bits,
        const _Float16* __restrict__ w16, const _Float16* __restrict__ r16,
        const _Float16* __restrict__ Rq, const int* __restrict__ T,
        float* __restrict__ out) {
    constexpr int CHN = L_N / CN;                // 64 or 32 steps per chunk
    constexpr int CSH = (CN == 16) ? 4 : 5;
    constexpr int NV  = (CHN * M_N) / (8 * 256); // uint4 per thread per table
    __shared__ _Float16 wbuf[CHN * M_N];         // 16KB or 8KB
    __shared__ _Float16 rbuf[CHN * M_N];
    int c = blockIdx.x & (CN - 1);
    int bblk = blockIdx.x >> CSH;
    int lane = threadIdx.x & 63, wid = threadIdx.x >> 6;
    int s = lane & 7, grp = lane >> 3;
    int q = s & 3;
    int b0 = bblk * 128 + wid * 32 + grp * 4;

    // stage chunk tables (coalesced uint4)
    {
        const uint4* sw = (const uint4*)(w16 + (size_t)c * CHN * M_N);
        const uint4* sr = (const uint4*)(r16 + (size_t)c * CHN * M_N);
        uint4* dw = (uint4*)wbuf; uint4* dr = (uint4*)rbuf;
        #pragma unroll
        for (int t = 0; t < NV; ++t) {
            dw[threadIdx.x + t * 256] = sw[threadIdx.x + t * 256];
            dr[threadIdx.x + t * 256] = sr[threadIdx.x + t * 256];
        }
    }

    // prefix load: R2[k][j] = packed pair for b0+(q^k), m = s*16+2j
    HU R2[4][8];
    u64 wb[4];
    const int word0 = (c * CHN) >> 6;            // u64 word holding this chunk
    const int hs0 = (c * CHN >> 5) & 1;          // starting 32-bit half
    #pragma unroll
    for (int k = 0; k < 4; ++k) {
        int b = b0 + (q ^ k);
        union { uint4 v[2]; uint32 w[8]; } P;
        const uint4* src = (const uint4*)(Rq + ((size_t)c * B_N + b) * M_N + s * 16);
        P.v[0] = src[0]; P.v[1] = src[1];
        #pragma unroll
        for (int j = 0; j < 8; ++j) R2[k][j].u = P.w[j];
        wb[k] = bits[(size_t)b * 16 + word0];
    }
    int Tb = T[b0 + q];

    __syncthreads();

    const float LOG2E2 = 2.885390082f; // 2*log2(e)
    const float NHL2 = -0.3465735903f; // -0.5*ln2
    float sum = 0.f;
    #pragma unroll
    for (int h = 0; h < CHN / 32; ++h) {
        int sh = ((hs0 + h) & 1) * 32;
        uint32 wh[4];
        #pragma unroll
        for (int k = 0; k < 4; ++k) wh[k] = (uint32)(wb[k] >> sh);
        uint32 ows = ~wh[0];                   // own b's word; bit==0 -> flip sign
        int rel = Tb - (c * CHN + h * 32);
        uint32 vmask = (rel <= 0) ? 0u : ((rel >= 32) ? 0xFFFFFFFFu : ((1u << rel) - 1u));

        for (int tt = 0; tt < 32; ++tt) {
            int base = (h * 32 + tt) * M_N + s * 16;
            union { uint4 q4[2]; uint32 w[8]; h2 v2[8]; } W, Rm;
            W.q4[0] = *(const uint4*)&wbuf[base];
            W.q4[1] = *((const uint4*)&wbuf[base] + 1);
            Rm.q4[0] = *(const uint4*)&rbuf[base];
            Rm.q4[1] = *((const uint4*)&rbuf[base] + 1);

            float d[4];
            #pragma unroll
            for (int k = 0; k < 4; ++k) {
                float acc = 0.f;
                #pragma unroll
                for (int j = 0; j < 8; ++j) acc = fdot2(R2[k][j].v2, W.v2[j], acc);
                d[k] = acc;
            }
            // select-free butterfly: each stage's partner holds OUR b's partial
            float xa = dpp_add<0xB1>(d[0], d[1]);   // + lane s^1 (its d[1] = our b)
            float xb = dpp_add<0xB1>(d[2], d[3]);   // partial for b^2
            float uD = dpp_add<0x4E>(xa, xb);       // + lane s^2 (its xb = our b)
            uD = dpp_add<0x104>(uD, uD);            // + lane s+4 (row_shl:4)

            // softplus: -0.5*ln2 * log2(1 + 2^(2*log2e*y)), y = +-D by sign-xor
            uint32 sgn = bfe1(ows, tt) & 0x80000000u;
            float y = uas_f(fas_u(uD) ^ sgn);
            float contr = NHL2 * log2_n(1.f + exp2_n(LOG2E2 * y));
            sum += uas_f(fas_u(contr) & bfe1(vmask, tt));

            // update: R2 *= (1 + (r-1)&mask)  (bfe mask + AND + packed fma)
            #pragma unroll
            for (int k = 0; k < 4; ++k) {
                uint32 msk = bfe1(wh[k], tt);
                #pragma unroll
                for (int j = 0; j < 8; ++j) {
                    HU sel; sel.u = Rm.w[j] & msk;
                    R2[k][j].v2 += sel.v2 * R2[k][j].v2;
                }
            }
        }
    }
    if (s < 4) atomicAdd(&out[b0 + s], sum);
}

extern "C" void kernel_launch(void* const* d_in, const int* in_sizes, int n_in,
                              void* d_out, int out_size, void* d_ws, size_t ws_size,
                              hipStream_t stream) {
    const int*   inputs  = (const int*)d_in[0];     // (B, L) int32
    const float* epsilon = (const float*)d_in[1];   // (D, M, L) f32
    float* out = (float*)d_out;                     // (B,) f32

    char* ws = (char*)d_ws;
    _Float16* w16 = (_Float16*)(ws + OFF_W16);
    _Float16* r16 = (_Float16*)(ws + OFF_R16);
    u64*   bits   = (u64*)  (ws + OFF_BITS);
    unsigned short* lrT = (unsigned short*)(ws + OFF_LR);
    int*   T      = (int*)  (ws + OFF_T);
    _Float16* Rq  = (_Float16*)(ws + OFF_RQ);

    k_prep<<<PACK_BLK + EPS_BLK + ZERO_BLK, 256, 0, stream>>>(
        inputs, epsilon, bits, w16, r16, lrT, out);

    // CN=32 needs 64MB Rq (high-water ~69MB); fall back to proven CN=16 if
    // the workspace can't hold it.
    const size_t need32 = (size_t)OFF_RQ + (size_t)32 * B_N * M_N * 2;
    if (ws_size >= need32) {
        k_slog2<32><<<1024 + 32, 256, 0, stream>>>(bits, lrT, Rq, T);
        k_main<32><<<(B_N / 128) * 32, 256, 0, stream>>>(bits, w16, r16, Rq, T, out);
    } else {
        k_slog2<16><<<1024 + 32, 256, 0, stream>>>(bits, lrT, Rq, T);
        k_main<16><<<(B_N / 128) * 16, 256, 0, stream>>>(bits, w16, r16, Rq, T, out);
    }
}

// Round 9
// 170.290 us; speedup vs baseline: 1.0501x; 1.0089x over previous
//
#include <hip/hip_runtime.h>
#include <hip/hip_fp16.h>

typedef unsigned long long u64;
typedef unsigned int uint32;
typedef short short8 __attribute__((ext_vector_type(8)));
typedef float f32x4 __attribute__((ext_vector_type(4)));
typedef _Float16 h2 __attribute__((ext_vector_type(2)));

#define B_N 8192
#define L_N 1024
#define M_N 128
#define HALF_N 512

// ws layout (bytes). T moved before Rq so Rq can grow.
#define OFF_W16  0           // w16[i][m] fp16: 256KB
#define OFF_R16  0x40000     // r16[i][m] fp16 (stores r-1): 256KB
#define OFF_BITS 0x80000     // bits[b][16] u64: 1MB
#define OFF_LR   0x180000    // lrT[m][t] bf16: 256KB
#define OFF_T    0x1C0000    // T[b] int32: 32KB
#define OFF_RQ   0x200000    // Rq[cn][b][m] fp16: 32MB (cn=16) or 64MB (cn=32)

#define PACK_BLK 2048
#define PACK_IT  16          // 2048*256*16 = B*L
#define EPS_BLK  32
#define ZERO_BLK 32

__device__ __forceinline__ unsigned short f32_bf16(float f) {
    union { float f; unsigned u; } x; x.f = f;
    unsigned u = x.u + 0x7FFFu + ((x.u >> 16) & 1u);   // RNE
    return (unsigned short)(u >> 16);
}

__device__ __forceinline__ float fdot2(h2 a, h2 b, float c) {
#if __has_builtin(__builtin_amdgcn_fdot2)
    return __builtin_amdgcn_fdot2(a, b, c, false);
#else
    return (float)a[0] * (float)b[0] + (float)a[1] * (float)b[1] + c;
#endif
}

__device__ __forceinline__ uint32 fas_u(float f) { union { float f; uint32 u; } x; x.f = f; return x.u; }
__device__ __forceinline__ float uas_f(uint32 u) { union { uint32 u; float f; } x; x.u = u; return x.f; }

// single-instr raw transcendentals (v_exp_f32 / v_log_f32); range proven
// finite by the passing runs of the same formula.
__device__ __forceinline__ float exp2_n(float x) {
#if __has_builtin(__builtin_amdgcn_exp2f)
    return __builtin_amdgcn_exp2f(x);
#else
    return exp2f(x);
#endif
}
__device__ __forceinline__ float log2_n(float x) {
#if __has_builtin(__builtin_amdgcn_logf)
    return __builtin_amdgcn_logf(x);
#else
    return __log2f(x);
#endif
}
// sign-extended single-bit extract: 0 or 0xFFFFFFFF (v_bfe_i32, 1 instr)
__device__ __forceinline__ uint32 bfe1(uint32 v, int off) {
#if __has_builtin(__builtin_amdgcn_sbfe)
    return (uint32)__builtin_amdgcn_sbfe((int)v, off, 1);
#else
    return (uint32)((int)(v << (31 - off)) >> 31);
#endif
}

// x + dpp(y). CTRL: 0xB1 = quad_perm[1,0,3,2] (xor1), 0x4E = quad_perm[2,3,0,1]
// (xor2), 0x104 = row_shl:4 (dest[i]=src[i+4]) — all HW-proven in r3/r4/r5.
template<int CTRL>
__device__ __forceinline__ float dpp_add(float x, float y) {
    union { float f; int i; } a, r;
    a.f = y;
    r.i = __builtin_amdgcn_update_dpp(0, a.i, CTRL, 0xF, 0xF, true);
    return x + r.f;
}

union HU { uint32 u; __half2 hh; h2 v2; };

// ---- K0: fused prep: spin-pack | eps tables (fp16) | zero out -----------
__global__ __launch_bounds__(256) void k_prep(const int* __restrict__ inp,
        const float* __restrict__ eps, u64* __restrict__ bits,
        _Float16* __restrict__ w16, _Float16* __restrict__ r16,
        unsigned short* __restrict__ lrT, float* __restrict__ out) {
    int bid = blockIdx.x;
    if (bid < PACK_BLK) {
        int g = bid * 256 + threadIdx.x;
        const int stride = PACK_BLK * 256;
        #pragma unroll 4
        for (int it = 0; it < PACK_IT; ++it) {
            int v = inp[g];
            u64 m = __ballot(v != 0);
            if ((threadIdx.x & 63) == 0) bits[g >> 6] = m;
            g += stride;
        }
        return;
    }
    bid -= PACK_BLK;
    if (bid < EPS_BLK) {
        int wid = threadIdx.x >> 6, lane = threadIdx.x & 63;
        int m = bid * 4 + wid;
        const float* e0 = eps + (size_t)m * L_N + lane * 16;
        const float* e1 = eps + (size_t)(M_N + m) * L_N + lane * 16;
        float a[16], b[16];
        #pragma unroll
        for (int j = 0; j < 16; j += 4) {
            *(float4*)&a[j] = *(const float4*)&e0[j];
            *(float4*)&b[j] = *(const float4*)&e1[j];
        }
        float local = 1.f;
        #pragma unroll
        for (int j = 0; j < 16; ++j) local *= a[j];
        float sc = local;
        #pragma unroll
        for (int d = 1; d < 64; d <<= 1) {
            float up = __shfl_up(sc, d);
            if (lane >= d) sc *= up;
        }
        float prev = __shfl_up(sc, 1);
        float E = (lane == 0) ? 1.f : prev;
        int i0 = lane * 16;
        #pragma unroll
        for (int j = 0; j < 16; ++j) {
            float rat = b[j] / a[j];
            w16[(size_t)(i0 + j) * M_N + m] = (_Float16)(E * (a[j] - b[j]));
            r16[(size_t)(i0 + j) * M_N + m] = (_Float16)(rat - 1.f);   // r-1 for pk_fma
            lrT[(size_t)m * L_N + i0 + j] = f32_bf16(__log2f(rat));
            E *= a[j];
        }
        return;
    }
    bid -= EPS_BLK;
    if (bid < ZERO_BLK) {
        out[bid * 256 + threadIdx.x] = 0.f;
    }
}

// ---- K2: MFMA chunk log-sums + f32 cumsum + exp2 -> fp16 excl prefix ----
// blocks [0,1024): prefix at CN granularity; [1024,1056): saturation T.
template<int CN>
__global__ __launch_bounds__(256) void k_slog2(const u64* __restrict__ bits,
        const unsigned short* __restrict__ lrT, _Float16* __restrict__ Rq,
        int* __restrict__ T) {
    if (blockIdx.x >= 1024) {
        int b = (blockIdx.x - 1024) * 256 + threadIdx.x;
        const u64* brow = bits + (size_t)b * 16;
        int n1 = 0, n0 = 0, Tv = 1024;
        for (int wd = 0; wd < 16; ++wd) {
            u64 x = brow[wd];
            int pc = __popcll(x);
            if (n1 + pc < HALF_N && n0 + (64 - pc) < HALF_N) {
                n1 += pc; n0 += 64 - pc;
                continue;
            }
            int found = 0;
            for (int k = 0; k < 64; ++k) {
                if (n1 >= HALF_N || n0 >= HALF_N) { Tv = wd * 64 + k; found = 1; break; }
                int sb = (int)((x >> k) & 1);
                n1 += sb; n0 += 1 - sb;
            }
            if (!found) Tv = (wd + 1) * 64;
            break;
        }
        T[b] = Tv;
        return;
    }
    int btile = blockIdx.x >> 1;
    int half = blockIdx.x & 1;
    int wid = threadIdx.x >> 6, lane = threadIdx.x & 63;
    int col = lane & 15, quad = lane >> 4;
    int m = (half * 4 + wid) * 16 + col;
    int b_row = btile * 16 + col;
    const u64* brow = bits + (size_t)b_row * 16;
    const unsigned short* lrow = lrT + (size_t)m * L_N;

    f32x4 cum = (f32x4){0.f, 0.f, 0.f, 0.f};

    for (int w = 0; w < 16; ++w) {
        u64 wv = brow[w];
        #pragma unroll
        for (int hf = 0; hf < 2; ++hf) {
            if (CN == 32 || hf == 0) {
                int cc = (CN == 32) ? (w * 2 + hf) : w;
                #pragma unroll
                for (int reg = 0; reg < 4; ++reg) {
                    int b = btile * 16 + quad * 4 + reg;
                    Rq[((size_t)cc * B_N + b) * M_N + m] = (_Float16)exp2_n(cum[reg]);
                }
            }
            short8 a;
            #pragma unroll
            for (int j = 0; j < 8; ++j)
                a[j] = (short)((((wv >> (hf * 32 + quad * 8 + j)) & 1) != 0) ? 0x3F80 : 0);
            union { uint4 u; short8 s; } bf;
            bf.u = *(const uint4*)(lrow + w * 64 + hf * 32 + quad * 8);
            cum = __builtin_amdgcn_mfma_f32_16x16x32_bf16(a, bf.s, cum, 0, 0, 0);
        }
    }
}

// ------- K3: main loop — R8 body + guaranteed v_pk_fma_f16 (__hfma2) + ---
// one-step LDS prefetch (unroll 2 elides the rotation copies).
template<int CN>
__global__ __launch_bounds__(256) __attribute__((amdgpu_waves_per_eu(1, 4)))
void k_main(const u64* __restrict__ bits,
        const _Float16* __restrict__ w16, const _Float16* __restrict__ r16,
        const _Float16* __restrict__ Rq, const int* __restrict__ T,
        float* __restrict__ out) {
    constexpr int CHN = L_N / CN;                // 64 or 32 steps per chunk
    constexpr int CSH = (CN == 16) ? 4 : 5;
    constexpr int NV  = (CHN * M_N) / (8 * 256); // uint4 per thread per table
    __shared__ _Float16 wbuf[CHN * M_N];         // 16KB or 8KB
    __shared__ _Float16 rbuf[CHN * M_N];
    int c = blockIdx.x & (CN - 1);
    int bblk = blockIdx.x >> CSH;
    int lane = threadIdx.x & 63, wid = threadIdx.x >> 6;
    int s = lane & 7, grp = lane >> 3;
    int q = s & 3;
    int b0 = bblk * 128 + wid * 32 + grp * 4;

    // stage chunk tables (coalesced uint4)
    {
        const uint4* sw = (const uint4*)(w16 + (size_t)c * CHN * M_N);
        const uint4* sr = (const uint4*)(r16 + (size_t)c * CHN * M_N);
        uint4* dw = (uint4*)wbuf; uint4* dr = (uint4*)rbuf;
        #pragma unroll
        for (int t = 0; t < NV; ++t) {
            dw[threadIdx.x + t * 256] = sw[threadIdx.x + t * 256];
            dr[threadIdx.x + t * 256] = sr[threadIdx.x + t * 256];
        }
    }

    // prefix load: R2[k][j] = packed pair for b0+(q^k), m = s*16+2j
    HU R2[4][8];
    u64 wb[4];
    const int word0 = (c * CHN) >> 6;            // u64 word holding this chunk
    const int hs0 = (c * CHN >> 5) & 1;          // starting 32-bit half
    #pragma unroll
    for (int k = 0; k < 4; ++k) {
        int b = b0 + (q ^ k);
        union { uint4 v[2]; uint32 w[8]; } P;
        const uint4* src = (const uint4*)(Rq + ((size_t)c * B_N + b) * M_N + s * 16);
        P.v[0] = src[0]; P.v[1] = src[1];
        #pragma unroll
        for (int j = 0; j < 8; ++j) R2[k][j].u = P.w[j];
        wb[k] = bits[(size_t)b * 16 + word0];
    }
    int Tb = T[b0 + q];

    __syncthreads();

    const float LOG2E2 = 2.885390082f; // 2*log2(e)
    const float NHL2 = -0.3465735903f; // -0.5*ln2
    float sum = 0.f;
    #pragma unroll
    for (int h = 0; h < CHN / 32; ++h) {
        int sh = ((hs0 + h) & 1) * 32;
        uint32 wh[4];
        #pragma unroll
        for (int k = 0; k < 4; ++k) wh[k] = (uint32)(wb[k] >> sh);
        uint32 ows = ~wh[0];                   // own b's word; bit==0 -> flip sign
        int rel = Tb - (c * CHN + h * 32);
        uint32 vmask = (rel <= 0) ? 0u : ((rel >= 32) ? 0xFFFFFFFFu : ((1u << rel) - 1u));

        // preload step 0 of this h (software pipeline, depth 1)
        int pb = (h * 32) * M_N + s * 16;
        uint4 Wc0 = *(const uint4*)&wbuf[pb];
        uint4 Wc1 = *((const uint4*)&wbuf[pb] + 1);
        uint4 Rc0 = *(const uint4*)&rbuf[pb];
        uint4 Rc1 = *((const uint4*)&rbuf[pb] + 1);

        #pragma unroll 2
        for (int tt = 0; tt < 32; ++tt) {
            // issue next step's LDS reads early (wrap: last iter's prefetch
            // reads valid step-0 data and is discarded)
            int bn = (h * 32 + ((tt + 1) & 31)) * M_N + s * 16;
            uint4 Wn0 = *(const uint4*)&wbuf[bn];
            uint4 Wn1 = *((const uint4*)&wbuf[bn] + 1);
            uint4 Rn0 = *(const uint4*)&rbuf[bn];
            uint4 Rn1 = *((const uint4*)&rbuf[bn] + 1);

            union { uint4 q4[2]; uint32 w[8]; h2 v2[8]; __half2 hh[8]; } W, Rm;
            W.q4[0] = Wc0; W.q4[1] = Wc1;
            Rm.q4[0] = Rc0; Rm.q4[1] = Rc1;

            float d[4];
            #pragma unroll
            for (int k = 0; k < 4; ++k) {
                float acc = 0.f;
                #pragma unroll
                for (int j = 0; j < 8; ++j) acc = fdot2(R2[k][j].v2, W.v2[j], acc);
                d[k] = acc;
            }
            // select-free butterfly: each stage's partner holds OUR b's partial
            float xa = dpp_add<0xB1>(d[0], d[1]);   // + lane s^1 (its d[1] = our b)
            float xb = dpp_add<0xB1>(d[2], d[3]);   // partial for b^2
            float uD = dpp_add<0x4E>(xa, xb);       // + lane s^2 (its xb = our b)
            uD = dpp_add<0x104>(uD, uD);            // + lane s+4 (row_shl:4)

            // softplus: -0.5*ln2 * log2(1 + 2^(2*log2e*y)), y = +-D by sign-xor
            uint32 sgn = bfe1(ows, tt) & 0x80000000u;
            float y = uas_f(fas_u(uD) ^ sgn);
            float contr = NHL2 * log2_n(1.f + exp2_n(LOG2E2 * y));
            sum += uas_f(fas_u(contr) & bfe1(vmask, tt));

            // update: R2 *= (1 + (r-1)&mask) — guaranteed v_pk_fma_f16
            #pragma unroll
            for (int k = 0; k < 4; ++k) {
                uint32 msk = bfe1(wh[k], tt);
                #pragma unroll
                for (int j = 0; j < 8; ++j) {
                    HU sel; sel.u = Rm.w[j] & msk;
                    R2[k][j].hh = __hfma2(sel.hh, R2[k][j].hh, R2[k][j].hh);
                }
            }

            Wc0 = Wn0; Wc1 = Wn1; Rc0 = Rn0; Rc1 = Rn1;
        }
    }
    if (s < 4) atomicAdd(&out[b0 + s], sum);
}

extern "C" void kernel_launch(void* const* d_in, const int* in_sizes, int n_in,
                              void* d_out, int out_size, void* d_ws, size_t ws_size,
                              hipStream_t stream) {
    const int*   inputs  = (const int*)d_in[0];     // (B, L) int32
    const float* epsilon = (const float*)d_in[1];   // (D, M, L) f32
    float* out = (float*)d_out;                     // (B,) f32

    char* ws = (char*)d_ws;
    _Float16* w16 = (_Float16*)(ws + OFF_W16);
    _Float16* r16 = (_Float16*)(ws + OFF_R16);
    u64*   bits   = (u64*)  (ws + OFF_BITS);
    unsigned short* lrT = (unsigned short*)(ws + OFF_LR);
    int*   T      = (int*)  (ws + OFF_T);
    _Float16* Rq  = (_Float16*)(ws + OFF_RQ);

    k_prep<<<PACK_BLK + EPS_BLK + ZERO_BLK, 256, 0, stream>>>(
        inputs, epsilon, bits, w16, r16, lrT, out);

    // CN=32 needs 64MB Rq (high-water ~69MB); fall back to proven CN=16 if
    // the workspace can't hold it.
    const size_t need32 = (size_t)OFF_RQ + (size_t)32 * B_N * M_N * 2;
    if (ws_size >= need32) {
        k_slog2<32><<<1024 + 32, 256, 0, stream>>>(bits, lrT, Rq, T);
        k_main<32><<<(B_N / 128) * 32, 256, 0, stream>>>(bits, w16, r16, Rq, T, out);
    } else {
        k_slog2<16><<<1024 + 32, 256, 0, stream>>>(bits, lrT, Rq, T);
        k_main<16><<<(B_N / 128) * 16, 256, 0, stream>>>(bits, w16, r16, Rq, T, out);
    }
}

// Round 10
// 163.446 us; speedup vs baseline: 1.0940x; 1.0419x over previous
//
#include <hip/hip_runtime.h>
#include <hip/hip_fp16.h>

typedef unsigned long long u64;
typedef unsigned int uint32;
typedef short short8 __attribute__((ext_vector_type(8)));
typedef float f32x4 __attribute__((ext_vector_type(4)));
typedef _Float16 h2 __attribute__((ext_vector_type(2)));

#define B_N 8192
#define L_N 1024
#define M_N 128
#define HALF_N 512

// ws layout (bytes)
#define OFF_WE   0x0         // wE[u][m] fp16, even-step weights: 128KB
#define OFF_WO   0x20000     // wO[u][2][m] fp16, odd weights {w, w*r_e}: 256KB
#define OFF_CMB  0x60000     // cmb[u][4][m] fp16, pair-update {0,ra-1,rb-1,rab-1}: 512KB
#define OFF_LR   0xE0000     // lrT[m][t] bf16: 256KB
#define OFF_BITS 0x120000    // bits[b][16] u64: 1MB
#define OFF_T    0x220000    // T[b] int32: 32KB
#define OFF_RQ   0x240000    // Rq[cn][b][m] fp16: 32MB (cn=16) or 64MB (cn=32)

#define PACK_BLK 2048
#define PACK_IT  16          // 2048*256*16 = B*L
#define EPS_BLK  32
#define ZERO_BLK 32

__device__ __forceinline__ unsigned short f32_bf16(float f) {
    union { float f; unsigned u; } x; x.f = f;
    unsigned u = x.u + 0x7FFFu + ((x.u >> 16) & 1u);   // RNE
    return (unsigned short)(u >> 16);
}

__device__ __forceinline__ float fdot2(h2 a, h2 b, float c) {
#if __has_builtin(__builtin_amdgcn_fdot2)
    return __builtin_amdgcn_fdot2(a, b, c, false);
#else
    return (float)a[0] * (float)b[0] + (float)a[1] * (float)b[1] + c;
#endif
}

__device__ __forceinline__ uint32 fas_u(float f) { union { float f; uint32 u; } x; x.f = f; return x.u; }
__device__ __forceinline__ float uas_f(uint32 u) { union { uint32 u; float f; } x; x.u = u; return x.f; }

__device__ __forceinline__ float exp2_n(float x) {
#if __has_builtin(__builtin_amdgcn_exp2f)
    return __builtin_amdgcn_exp2f(x);
#else
    return exp2f(x);
#endif
}
__device__ __forceinline__ float log2_n(float x) {
#if __has_builtin(__builtin_amdgcn_logf)
    return __builtin_amdgcn_logf(x);
#else
    return __log2f(x);
#endif
}
// sign-extended single-bit extract: 0 or 0xFFFFFFFF
__device__ __forceinline__ uint32 bfe1(uint32 v, int off) {
#if __has_builtin(__builtin_amdgcn_sbfe)
    return (uint32)__builtin_amdgcn_sbfe((int)v, off, 1);
#else
    return (uint32)((int)(v << (31 - off)) >> 31);
#endif
}
// unsigned 2-bit extract (the pair's combo index; bits are adjacent)
__device__ __forceinline__ uint32 ubfe2(uint32 v, int off) {
#if __has_builtin(__builtin_amdgcn_ubfe)
    return (uint32)__builtin_amdgcn_ubfe((int)v, off, 2);
#else
    return (v >> off) & 3u;
#endif
}

// x + dpp(y). CTRL: 0xB1 = quad_perm[1,0,3,2], 0x4E = quad_perm[2,3,0,1],
// 0x104 = row_shl:4 — all HW-proven in r3/r4/r5.
template<int CTRL>
__device__ __forceinline__ float dpp_add(float x, float y) {
    union { float f; int i; } a, r;
    a.f = y;
    r.i = __builtin_amdgcn_update_dpp(0, a.i, CTRL, 0xF, 0xF, true);
    return x + r.f;
}

union HU { uint32 u; __half2 hh; h2 v2; };

// ---- K0: fused prep: spin-pack | pair tables (fp16) | zero out ----------
__global__ __launch_bounds__(256) void k_prep(const int* __restrict__ inp,
        const float* __restrict__ eps, u64* __restrict__ bits,
        _Float16* __restrict__ wE, _Float16* __restrict__ wO,
        _Float16* __restrict__ cmb,
        unsigned short* __restrict__ lrT, float* __restrict__ out) {
    int bid = blockIdx.x;
    if (bid < PACK_BLK) {
        int g = bid * 256 + threadIdx.x;
        const int stride = PACK_BLK * 256;
        #pragma unroll 4
        for (int it = 0; it < PACK_IT; ++it) {
            int v = inp[g];
            u64 m = __ballot(v != 0);
            if ((threadIdx.x & 63) == 0) bits[g >> 6] = m;
            g += stride;
        }
        return;
    }
    bid -= PACK_BLK;
    if (bid < EPS_BLK) {
        int wid = threadIdx.x >> 6, lane = threadIdx.x & 63;
        int m = bid * 4 + wid;
        const float* e0 = eps + (size_t)m * L_N + lane * 16;
        const float* e1 = eps + (size_t)(M_N + m) * L_N + lane * 16;
        float a[16], b[16];
        #pragma unroll
        for (int j = 0; j < 16; j += 4) {
            *(float4*)&a[j] = *(const float4*)&e0[j];
            *(float4*)&b[j] = *(const float4*)&e1[j];
        }
        float local = 1.f;
        #pragma unroll
        for (int j = 0; j < 16; ++j) local *= a[j];
        float sc = local;
        #pragma unroll
        for (int d = 1; d < 64; d <<= 1) {
            float up = __shfl_up(sc, d);
            if (lane >= d) sc *= up;
        }
        float prev = __shfl_up(sc, 1);
        float E = (lane == 0) ? 1.f : prev;
        int i0 = lane * 16;                     // even (x16)
        float rat_e = 1.f;
        #pragma unroll
        for (int j = 0; j < 16; ++j) {
            float rat = b[j] / a[j];
            float w = E * (a[j] - b[j]);
            lrT[(size_t)m * L_N + i0 + j] = f32_bf16(__log2f(rat));
            int u = (i0 + j) >> 1;
            if ((j & 1) == 0) {
                wE[(size_t)u * M_N + m] = (_Float16)w;
                rat_e = rat;
            } else {
                _Float16* wo = wO + (size_t)u * 2 * M_N;
                wo[m]       = (_Float16)w;              // bit0=0: plain w(odd)
                wo[M_N + m] = (_Float16)(w * rat_e);    // bit0=1: w(odd)*r(even)
                _Float16* cr = cmb + (size_t)u * 4 * M_N;
                cr[m]           = (_Float16)0.f;                    // 00
                cr[M_N + m]     = (_Float16)(rat_e - 1.f);          // 01: r_a-1
                cr[2*M_N + m]   = (_Float16)(rat - 1.f);            // 10: r_b-1
                cr[3*M_N + m]   = (_Float16)(rat_e * rat - 1.f);    // 11
            }
            E *= a[j];
        }
        return;
    }
    bid -= EPS_BLK;
    if (bid < ZERO_BLK) {
        out[bid * 256 + threadIdx.x] = 0.f;
    }
}

// ---- K2: MFMA chunk log-sums + f32 cumsum + exp2 -> fp16 excl prefix ----
// blocks [0,1024): prefix at CN granularity; [1024,1056): saturation T.
template<int CN>
__global__ __launch_bounds__(256) void k_slog2(const u64* __restrict__ bits,
        const unsigned short* __restrict__ lrT, _Float16* __restrict__ Rq,
        int* __restrict__ T) {
    if (blockIdx.x >= 1024) {
        int b = (blockIdx.x - 1024) * 256 + threadIdx.x;
        const u64* brow = bits + (size_t)b * 16;
        int n1 = 0, n0 = 0, Tv = 1024;
        for (int wd = 0; wd < 16; ++wd) {
            u64 x = brow[wd];
            int pc = __popcll(x);
            if (n1 + pc < HALF_N && n0 + (64 - pc) < HALF_N) {
                n1 += pc; n0 += 64 - pc;
                continue;
            }
            int found = 0;
            for (int k = 0; k < 64; ++k) {
                if (n1 >= HALF_N || n0 >= HALF_N) { Tv = wd * 64 + k; found = 1; break; }
                int sb = (int)((x >> k) & 1);
                n1 += sb; n0 += 1 - sb;
            }
            if (!found) Tv = (wd + 1) * 64;
            break;
        }
        T[b] = Tv;
        return;
    }
    int btile = blockIdx.x >> 1;
    int half = blockIdx.x & 1;
    int wid = threadIdx.x >> 6, lane = threadIdx.x & 63;
    int col = lane & 15, quad = lane >> 4;
    int m = (half * 4 + wid) * 16 + col;
    int b_row = btile * 16 + col;
    const u64* brow = bits + (size_t)b_row * 16;
    const unsigned short* lrow = lrT + (size_t)m * L_N;

    f32x4 cum = (f32x4){0.f, 0.f, 0.f, 0.f};

    for (int w = 0; w < 16; ++w) {
        u64 wv = brow[w];
        #pragma unroll
        for (int hf = 0; hf < 2; ++hf) {
            if (CN == 32 || hf == 0) {
                int cc = (CN == 32) ? (w * 2 + hf) : w;
                #pragma unroll
                for (int reg = 0; reg < 4; ++reg) {
                    int b = btile * 16 + quad * 4 + reg;
                    Rq[((size_t)cc * B_N + b) * M_N + m] = (_Float16)exp2_n(cum[reg]);
                }
            }
            short8 a;
            #pragma unroll
            for (int j = 0; j < 8; ++j)
                a[j] = (short)((((wv >> (hf * 32 + quad * 8 + j)) & 1) != 0) ? 0x3F80 : 0);
            union { uint4 u; short8 s; } bf;
            bf.u = *(const uint4*)(lrow + w * 64 + hf * 32 + quad * 8);
            cum = __builtin_amdgcn_mfma_f32_16x16x32_bf16(a, bf.s, cum, 0, 0, 0);
        }
    }
}

// ------- K3: main loop — pair-steps with combo tables --------------------
// Per pair u (steps 2u,2u+1): D(2u)=<R,wE>, D(2u+1)=<R,wO[bit0]> (weight
// pre-scaled by r(2u) when bit0=1), then ONE update R *= 1+cmb[combo] where
// combo = 2 adjacent bits. Bit-dependence moves from per-j VALU masks to
// per-k LDS addressing. k-permuted b's keep the butterfly select-free.
template<int CN>
__global__ __launch_bounds__(256) __attribute__((amdgpu_waves_per_eu(1, 4)))
void k_main(const u64* __restrict__ bits, const _Float16* __restrict__ wE,
        const _Float16* __restrict__ wO, const _Float16* __restrict__ cmb,
        const _Float16* __restrict__ Rq, const int* __restrict__ T,
        float* __restrict__ out) {
    constexpr int CHN = L_N / CN;                // 64 or 32 steps per chunk
    constexpr int PRS = CHN / 2;                 // pairs per chunk
    constexpr int CSH = (CN == 16) ? 4 : 5;
    constexpr int NE  = PRS * M_N / (8 * 256);   // uint4/thread for wE slice
    __shared__ _Float16 webuf[PRS * M_N];        // 4KB (CN32) / 8KB
    __shared__ _Float16 wobuf[PRS * 2 * M_N];    // 8KB / 16KB
    __shared__ _Float16 cbuf [PRS * 4 * M_N];    // 16KB / 32KB
    int c = blockIdx.x & (CN - 1);
    int bblk = blockIdx.x >> CSH;
    int lane = threadIdx.x & 63, wid = threadIdx.x >> 6;
    int s = lane & 7, grp = lane >> 3;
    int q = s & 3;
    int b0 = bblk * 128 + wid * 32 + grp * 4;

    // stage chunk tables (coalesced uint4)
    {
        const uint4* se = (const uint4*)(wE  + (size_t)c * PRS * M_N);
        const uint4* so = (const uint4*)(wO  + (size_t)c * PRS * 2 * M_N);
        const uint4* sc = (const uint4*)(cmb + (size_t)c * PRS * 4 * M_N);
        uint4* de = (uint4*)webuf; uint4* dd = (uint4*)wobuf; uint4* dc = (uint4*)cbuf;
        #pragma unroll
        for (int t = 0; t < NE; ++t)     de[threadIdx.x + t * 256] = se[threadIdx.x + t * 256];
        #pragma unroll
        for (int t = 0; t < 2 * NE; ++t) dd[threadIdx.x + t * 256] = so[threadIdx.x + t * 256];
        #pragma unroll
        for (int t = 0; t < 4 * NE; ++t) dc[threadIdx.x + t * 256] = sc[threadIdx.x + t * 256];
    }

    // prefix load: R2[k][j] = packed pair for b0+(q^k), m = s*16+2j
    HU R2[4][8];
    u64 wb[4];
    const int word0 = (c * CHN) >> 6;            // u64 word holding this chunk
    const int hs0 = (c * CHN >> 5) & 1;          // starting 32-bit half
    #pragma unroll
    for (int k = 0; k < 4; ++k) {
        int b = b0 + (q ^ k);
        union { uint4 v[2]; uint32 w[8]; } P;
        const uint4* src = (const uint4*)(Rq + ((size_t)c * B_N + b) * M_N + s * 16);
        P.v[0] = src[0]; P.v[1] = src[1];
        #pragma unroll
        for (int j = 0; j < 8; ++j) R2[k][j].u = P.w[j];
        wb[k] = bits[(size_t)b * 16 + word0];
    }
    int Tb = T[b0 + q];

    __syncthreads();

    const float LOG2E2 = 2.885390082f; // 2*log2(e)
    const float NHL2 = -0.3465735903f; // -0.5*ln2
    float sum = 0.f;
    #pragma unroll
    for (int h = 0; h < CHN / 32; ++h) {
        int sh = ((hs0 + h) & 1) * 32;
        uint32 wh[4];
        #pragma unroll
        for (int k = 0; k < 4; ++k) wh[k] = (uint32)(wb[k] >> sh);
        uint32 ows = ~wh[0];                   // own b's word; bit==0 -> flip sign
        int rel = Tb - (c * CHN + h * 32);
        uint32 vmask = (rel <= 0) ? 0u : ((rel >= 32) ? 0xFFFFFFFFu : ((1u << rel) - 1u));

        #pragma unroll 2
        for (int tt = 0; tt < 16; ++tt) {      // 16 pairs = 32 steps
            int p = h * 16 + tt;
            union U8 { uint4 q4[2]; uint32 w[8]; h2 v2[8]; __half2 hh[8]; };
            U8 WEu;
            const _Float16* web = &webuf[p * M_N + s * 16];
            WEu.q4[0] = *(const uint4*)web;
            WEu.q4[1] = *((const uint4*)web + 1);

            uint32 cbo[4];
            #pragma unroll
            for (int k = 0; k < 4; ++k) cbo[k] = ubfe2(wh[k], 2 * tt);

            // even dots: shared wE
            float de[4];
            #pragma unroll
            for (int k = 0; k < 4; ++k) {
                float acc = 0.f;
                #pragma unroll
                for (int j = 0; j < 8; ++j) acc = fdot2(R2[k][j].v2, WEu.v2[j], acc);
                de[k] = acc;
            }
            // odd dots: per-k bit0-selected weight row
            float dd[4];
            #pragma unroll
            for (int k = 0; k < 4; ++k) {
                U8 WOu;
                int ob = p * 2 * M_N + (int)((cbo[k] & 1u) << 7) + s * 16;
                WOu.q4[0] = *(const uint4*)&wobuf[ob];
                WOu.q4[1] = *((const uint4*)&wobuf[ob] + 1);
                float acc = 0.f;
                #pragma unroll
                for (int j = 0; j < 8; ++j) acc = fdot2(R2[k][j].v2, WOu.v2[j], acc);
                dd[k] = acc;
            }
            // butterflies (select-free via k-permute)
            float xe = dpp_add<0xB1>(de[0], de[1]);
            float ye = dpp_add<0xB1>(de[2], de[3]);
            float De = dpp_add<0x4E>(xe, ye);
            De = dpp_add<0x104>(De, De);
            float xo = dpp_add<0xB1>(dd[0], dd[1]);
            float yo = dpp_add<0xB1>(dd[2], dd[3]);
            float Do = dpp_add<0x4E>(xo, yo);
            Do = dpp_add<0x104>(Do, Do);

            // softplus x2 (steps 2tt, 2tt+1)
            uint32 sg0 = bfe1(ows, 2 * tt) & 0x80000000u;
            float y0 = uas_f(fas_u(De) ^ sg0);
            float c0 = NHL2 * log2_n(1.f + exp2_n(LOG2E2 * y0));
            sum += uas_f(fas_u(c0) & bfe1(vmask, 2 * tt));
            uint32 sg1 = bfe1(ows, 2 * tt + 1) & 0x80000000u;
            float y1 = uas_f(fas_u(Do) ^ sg1);
            float c1 = NHL2 * log2_n(1.f + exp2_n(LOG2E2 * y1));
            sum += uas_f(fas_u(c1) & bfe1(vmask, 2 * tt + 1));

            // ONE update per pair: R *= 1 + cmb[combo]  (combo 00 row is 0)
            #pragma unroll
            for (int k = 0; k < 4; ++k) {
                U8 CMu;
                int cb = p * 4 * M_N + (int)(cbo[k] << 7) + s * 16;
                CMu.q4[0] = *(const uint4*)&cbuf[cb];
                CMu.q4[1] = *((const uint4*)&cbuf[cb] + 1);
                #pragma unroll
                for (int j = 0; j < 8; ++j)
                    R2[k][j].hh = __hfma2(CMu.hh[j], R2[k][j].hh, R2[k][j].hh);
            }
        }
    }
    if (s < 4) atomicAdd(&out[b0 + s], sum);
}

extern "C" void kernel_launch(void* const* d_in, const int* in_sizes, int n_in,
                              void* d_out, int out_size, void* d_ws, size_t ws_size,
                              hipStream_t stream) {
    const int*   inputs  = (const int*)d_in[0];     // (B, L) int32
    const float* epsilon = (const float*)d_in[1];   // (D, M, L) f32
    float* out = (float*)d_out;                     // (B,) f32

    char* ws = (char*)d_ws;
    _Float16* wE  = (_Float16*)(ws + OFF_WE);
    _Float16* wO  = (_Float16*)(ws + OFF_WO);
    _Float16* cmb = (_Float16*)(ws + OFF_CMB);
    unsigned short* lrT = (unsigned short*)(ws + OFF_LR);
    u64*   bits   = (u64*)  (ws + OFF_BITS);
    int*   T      = (int*)  (ws + OFF_T);
    _Float16* Rq  = (_Float16*)(ws + OFF_RQ);

    k_prep<<<PACK_BLK + EPS_BLK + ZERO_BLK, 256, 0, stream>>>(
        inputs, epsilon, bits, wE, wO, cmb, lrT, out);

    // CN=32 needs 64MB Rq; fall back to CN=16 if the workspace can't hold it.
    const size_t need32 = (size_t)OFF_RQ + (size_t)32 * B_N * M_N * 2;
    if (ws_size >= need32) {
        k_slog2<32><<<1024 + 32, 256, 0, stream>>>(bits, lrT, Rq, T);
        k_main<32><<<(B_N / 128) * 32, 256, 0, stream>>>(bits, wE, wO, cmb, Rq, T, out);
    } else {
        k_slog2<16><<<1024 + 32, 256, 0, stream>>>(bits, lrT, Rq, T);
        k_main<16><<<(B_N / 128) * 16, 256, 0, stream>>>(bits, wE, wO, cmb, Rq, T, out);
    }
}

// Round 11
// 163.375 us; speedup vs baseline: 1.0945x; 1.0004x over previous
//
#include <hip/hip_runtime.h>
#include <hip/hip_fp16.h>

typedef unsigned long long u64;
typedef unsigned int uint32;
typedef short short8 __attribute__((ext_vector_type(8)));
typedef float f32x4 __attribute__((ext_vector_type(4)));
typedef _Float16 h2 __attribute__((ext_vector_type(2)));

#define B_N 8192
#define L_N 1024
#define M_N 128
#define HALF_N 512

// ws layout (bytes)
#define OFF_WE   0x0         // wE[u][m] fp16, even-step weights: 128KB
#define OFF_WO   0x20000     // wO[u][2][m] fp16, odd weights {w, w*r_e}: 256KB
#define OFF_CMB  0x60000     // cmb[u][4][m] fp16, pair-update {0,ra-1,rb-1,rab-1}: 512KB
#define OFF_LR   0xE0000     // lrT[m][t] bf16: 256KB
#define OFF_BITS 0x120000    // bits[b][16] u64: 1MB
#define OFF_T    0x220000    // T[b] int32: 32KB
#define OFF_RQ   0x240000    // Rq[cn][b][m] fp16: 32MB (cn=16) or 64MB (cn=32)

#define PACK_BLK 2048
#define PACK_IT  16          // 2048*256*16 = B*L
#define EPS_BLK  32
#define ZERO_BLK 32

__device__ __forceinline__ unsigned short f32_bf16(float f) {
    union { float f; unsigned u; } x; x.f = f;
    unsigned u = x.u + 0x7FFFu + ((x.u >> 16) & 1u);   // RNE
    return (unsigned short)(u >> 16);
}

__device__ __forceinline__ float fdot2(h2 a, h2 b, float c) {
#if __has_builtin(__builtin_amdgcn_fdot2)
    return __builtin_amdgcn_fdot2(a, b, c, false);
#else
    return (float)a[0] * (float)b[0] + (float)a[1] * (float)b[1] + c;
#endif
}

__device__ __forceinline__ uint32 fas_u(float f) { union { float f; uint32 u; } x; x.f = f; return x.u; }
__device__ __forceinline__ float uas_f(uint32 u) { union { uint32 u; float f; } x; x.u = u; return x.f; }

__device__ __forceinline__ float exp2_n(float x) {
#if __has_builtin(__builtin_amdgcn_exp2f)
    return __builtin_amdgcn_exp2f(x);
#else
    return exp2f(x);
#endif
}
__device__ __forceinline__ float log2_n(float x) {
#if __has_builtin(__builtin_amdgcn_logf)
    return __builtin_amdgcn_logf(x);
#else
    return __log2f(x);
#endif
}
// sign-extended single-bit extract: 0 or 0xFFFFFFFF
__device__ __forceinline__ uint32 bfe1(uint32 v, int off) {
#if __has_builtin(__builtin_amdgcn_sbfe)
    return (uint32)__builtin_amdgcn_sbfe((int)v, off, 1);
#else
    return (uint32)((int)(v << (31 - off)) >> 31);
#endif
}
// unsigned 2-bit extract (the pair's combo index; bits are adjacent)
__device__ __forceinline__ uint32 ubfe2(uint32 v, int off) {
#if __has_builtin(__builtin_amdgcn_ubfe)
    return (uint32)__builtin_amdgcn_ubfe((int)v, off, 2);
#else
    return (v >> off) & 3u;
#endif
}

// x + dpp(y). CTRL: 0xB1 = quad_perm[1,0,3,2], 0x4E = quad_perm[2,3,0,1],
// 0x104 = row_shl:4 — all HW-proven in r3/r4/r5.
template<int CTRL>
__device__ __forceinline__ float dpp_add(float x, float y) {
    union { float f; int i; } a, r;
    a.f = y;
    r.i = __builtin_amdgcn_update_dpp(0, a.i, CTRL, 0xF, 0xF, true);
    return x + r.f;
}

union HU { uint32 u; __half2 hh; h2 v2; };

// ---- K0: fused prep: spin-pack | pair tables (fp16) | zero out ----------
__global__ __launch_bounds__(256) void k_prep(const int* __restrict__ inp,
        const float* __restrict__ eps, u64* __restrict__ bits,
        _Float16* __restrict__ wE, _Float16* __restrict__ wO,
        _Float16* __restrict__ cmb,
        unsigned short* __restrict__ lrT, float* __restrict__ out) {
    int bid = blockIdx.x;
    if (bid < PACK_BLK) {
        int g = bid * 256 + threadIdx.x;
        const int stride = PACK_BLK * 256;
        #pragma unroll 4
        for (int it = 0; it < PACK_IT; ++it) {
            int v = inp[g];
            u64 m = __ballot(v != 0);
            if ((threadIdx.x & 63) == 0) bits[g >> 6] = m;
            g += stride;
        }
        return;
    }
    bid -= PACK_BLK;
    if (bid < EPS_BLK) {
        int wid = threadIdx.x >> 6, lane = threadIdx.x & 63;
        int m = bid * 4 + wid;
        const float* e0 = eps + (size_t)m * L_N + lane * 16;
        const float* e1 = eps + (size_t)(M_N + m) * L_N + lane * 16;
        float a[16], b[16];
        #pragma unroll
        for (int j = 0; j < 16; j += 4) {
            *(float4*)&a[j] = *(const float4*)&e0[j];
            *(float4*)&b[j] = *(const float4*)&e1[j];
        }
        float local = 1.f;
        #pragma unroll
        for (int j = 0; j < 16; ++j) local *= a[j];
        float sc = local;
        #pragma unroll
        for (int d = 1; d < 64; d <<= 1) {
            float up = __shfl_up(sc, d);
            if (lane >= d) sc *= up;
        }
        float prev = __shfl_up(sc, 1);
        float E = (lane == 0) ? 1.f : prev;
        int i0 = lane * 16;                     // even (x16)
        float rat_e = 1.f;
        #pragma unroll
        for (int j = 0; j < 16; ++j) {
            float rat = b[j] / a[j];
            float w = E * (a[j] - b[j]);
            lrT[(size_t)m * L_N + i0 + j] = f32_bf16(__log2f(rat));
            int u = (i0 + j) >> 1;
            if ((j & 1) == 0) {
                wE[(size_t)u * M_N + m] = (_Float16)w;
                rat_e = rat;
            } else {
                _Float16* wo = wO + (size_t)u * 2 * M_N;
                wo[m]       = (_Float16)w;              // bit0=0: plain w(odd)
                wo[M_N + m] = (_Float16)(w * rat_e);    // bit0=1: w(odd)*r(even)
                _Float16* cr = cmb + (size_t)u * 4 * M_N;
                cr[m]           = (_Float16)0.f;                    // 00
                cr[M_N + m]     = (_Float16)(rat_e - 1.f);          // 01: r_a-1
                cr[2*M_N + m]   = (_Float16)(rat - 1.f);            // 10: r_b-1
                cr[3*M_N + m]   = (_Float16)(rat_e * rat - 1.f);    // 11
            }
            E *= a[j];
        }
        return;
    }
    bid -= EPS_BLK;
    if (bid < ZERO_BLK) {
        out[bid * 256 + threadIdx.x] = 0.f;
    }
}

// ---- K2: MFMA chunk log-sums + f32 cumsum + exp2 -> fp16 excl prefix ----
// blocks [0,1024): prefix at CN granularity; [1024,1056): saturation T.
template<int CN>
__global__ __launch_bounds__(256) void k_slog2(const u64* __restrict__ bits,
        const unsigned short* __restrict__ lrT, _Float16* __restrict__ Rq,
        int* __restrict__ T) {
    if (blockIdx.x >= 1024) {
        int b = (blockIdx.x - 1024) * 256 + threadIdx.x;
        const u64* brow = bits + (size_t)b * 16;
        int n1 = 0, n0 = 0, Tv = 1024;
        for (int wd = 0; wd < 16; ++wd) {
            u64 x = brow[wd];
            int pc = __popcll(x);
            if (n1 + pc < HALF_N && n0 + (64 - pc) < HALF_N) {
                n1 += pc; n0 += 64 - pc;
                continue;
            }
            int found = 0;
            for (int k = 0; k < 64; ++k) {
                if (n1 >= HALF_N || n0 >= HALF_N) { Tv = wd * 64 + k; found = 1; break; }
                int sb = (int)((x >> k) & 1);
                n1 += sb; n0 += 1 - sb;
            }
            if (!found) Tv = (wd + 1) * 64;
            break;
        }
        T[b] = Tv;
        return;
    }
    int btile = blockIdx.x >> 1;
    int half = blockIdx.x & 1;
    int wid = threadIdx.x >> 6, lane = threadIdx.x & 63;
    int col = lane & 15, quad = lane >> 4;
    int m = (half * 4 + wid) * 16 + col;
    int b_row = btile * 16 + col;
    const u64* brow = bits + (size_t)b_row * 16;
    const unsigned short* lrow = lrT + (size_t)m * L_N;

    f32x4 cum = (f32x4){0.f, 0.f, 0.f, 0.f};

    for (int w = 0; w < 16; ++w) {
        u64 wv = brow[w];
        #pragma unroll
        for (int hf = 0; hf < 2; ++hf) {
            if (CN == 32 || hf == 0) {
                int cc = (CN == 32) ? (w * 2 + hf) : w;
                #pragma unroll
                for (int reg = 0; reg < 4; ++reg) {
                    int b = btile * 16 + quad * 4 + reg;
                    Rq[((size_t)cc * B_N + b) * M_N + m] = (_Float16)exp2_n(cum[reg]);
                }
            }
            short8 a;
            #pragma unroll
            for (int j = 0; j < 8; ++j)
                a[j] = (short)((((wv >> (hf * 32 + quad * 8 + j)) & 1) != 0) ? 0x3F80 : 0);
            union { uint4 u; short8 s; } bf;
            bf.u = *(const uint4*)(lrow + w * 64 + hf * 32 + quad * 8);
            cum = __builtin_amdgcn_mfma_f32_16x16x32_bf16(a, bf.s, cum, 0, 0, 0);
        }
    }
}

// ------- K3: main loop — pair-steps; bank-conflict-free padded rows ------
// Selected-row tables (wO, cmb) use LDS row stride 136 elem (272B = 68 dw
// == 4 mod 32 banks): adjacent rows shift 4 banks, so lanes picking
// different rows occupy disjoint bank windows (R10's 8.4M conflicts -> ~0).
template<int CN>
__global__ __launch_bounds__(256) __attribute__((amdgpu_waves_per_eu(1, 4)))
void k_main(const u64* __restrict__ bits, const _Float16* __restrict__ wE,
        const _Float16* __restrict__ wO, const _Float16* __restrict__ cmb,
        const _Float16* __restrict__ Rq, const int* __restrict__ T,
        float* __restrict__ out) {
    constexpr int CHN = L_N / CN;                // 64 or 32 steps per chunk
    constexpr int PRS = CHN / 2;                 // pairs per chunk
    constexpr int CSH = (CN == 16) ? 4 : 5;
    constexpr int NE  = PRS * M_N / (8 * 256);   // uint4/thread for wE slice
    constexpr int RST = 136;                     // padded row stride (elems)
    __shared__ _Float16 webuf[PRS * M_N];        // linear (broadcast reads)
    __shared__ _Float16 wobuf[PRS * 2 * RST];
    __shared__ _Float16 cbuf [PRS * 4 * RST];
    int c = blockIdx.x & (CN - 1);
    int bblk = blockIdx.x >> CSH;
    int lane = threadIdx.x & 63, wid = threadIdx.x >> 6;
    int s = lane & 7, grp = lane >> 3;
    int q = s & 3;
    int b0 = bblk * 128 + wid * 32 + grp * 4;

    // stage chunk tables. wE: linear. wO/cmb: row-padded — global uint4 t
    // (16 uint4 per 128-elem row) lands at LDS uint4 (t>>4)*17 + (t&15).
    {
        const uint4* se = (const uint4*)(wE  + (size_t)c * PRS * M_N);
        const uint4* so = (const uint4*)(wO  + (size_t)c * PRS * 2 * M_N);
        const uint4* sc = (const uint4*)(cmb + (size_t)c * PRS * 4 * M_N);
        uint4* de = (uint4*)webuf; uint4* dd = (uint4*)wobuf; uint4* dc = (uint4*)cbuf;
        #pragma unroll
        for (int t = 0; t < NE; ++t)
            de[threadIdx.x + t * 256] = se[threadIdx.x + t * 256];
        #pragma unroll
        for (int t = 0; t < 2 * NE; ++t) {
            int idx = threadIdx.x + t * 256;
            dd[(idx >> 4) * 17 + (idx & 15)] = so[idx];
        }
        #pragma unroll
        for (int t = 0; t < 4 * NE; ++t) {
            int idx = threadIdx.x + t * 256;
            dc[(idx >> 4) * 17 + (idx & 15)] = sc[idx];
        }
    }

    // prefix load: R2[k][j] = packed pair for b0+(q^k), m = s*16+2j
    HU R2[4][8];
    u64 wb[4];
    const int word0 = (c * CHN) >> 6;            // u64 word holding this chunk
    const int hs0 = (c * CHN >> 5) & 1;          // starting 32-bit half
    #pragma unroll
    for (int k = 0; k < 4; ++k) {
        int b = b0 + (q ^ k);
        union { uint4 v[2]; uint32 w[8]; } P;
        const uint4* src = (const uint4*)(Rq + ((size_t)c * B_N + b) * M_N + s * 16);
        P.v[0] = src[0]; P.v[1] = src[1];
        #pragma unroll
        for (int j = 0; j < 8; ++j) R2[k][j].u = P.w[j];
        wb[k] = bits[(size_t)b * 16 + word0];
    }
    int Tb = T[b0 + q];

    __syncthreads();

    const float LOG2E2 = 2.885390082f; // 2*log2(e)
    const float NHL2 = -0.3465735903f; // -0.5*ln2
    float sum = 0.f;
    #pragma unroll
    for (int h = 0; h < CHN / 32; ++h) {
        int sh = ((hs0 + h) & 1) * 32;
        uint32 wh[4];
        #pragma unroll
        for (int k = 0; k < 4; ++k) wh[k] = (uint32)(wb[k] >> sh);
        uint32 ows = ~wh[0];                   // own b's word; bit==0 -> flip sign
        int rel = Tb - (c * CHN + h * 32);
        uint32 vmask = (rel <= 0) ? 0u : ((rel >= 32) ? 0xFFFFFFFFu : ((1u << rel) - 1u));

        #pragma unroll 2
        for (int tt = 0; tt < 16; ++tt) {      // 16 pairs = 32 steps
            int p = h * 16 + tt;
            union U8 { uint4 q4[2]; uint32 w[8]; h2 v2[8]; __half2 hh[8]; };
            U8 WEu;
            const _Float16* web = &webuf[p * M_N + s * 16];
            WEu.q4[0] = *(const uint4*)web;
            WEu.q4[1] = *((const uint4*)web + 1);

            uint32 cbo[4];
            #pragma unroll
            for (int k = 0; k < 4; ++k) cbo[k] = ubfe2(wh[k], 2 * tt);

            // even dots: shared wE
            float de[4];
            #pragma unroll
            for (int k = 0; k < 4; ++k) {
                float acc = 0.f;
                #pragma unroll
                for (int j = 0; j < 8; ++j) acc = fdot2(R2[k][j].v2, WEu.v2[j], acc);
                de[k] = acc;
            }
            // odd dots: per-k bit0-selected weight row (padded stride)
            float dd[4];
            #pragma unroll
            for (int k = 0; k < 4; ++k) {
                U8 WOu;
                int ob = (p * 2 + (int)(cbo[k] & 1u)) * RST + s * 16;
                WOu.q4[0] = *(const uint4*)&wobuf[ob];
                WOu.q4[1] = *((const uint4*)&wobuf[ob] + 1);
                float acc = 0.f;
                #pragma unroll
                for (int j = 0; j < 8; ++j) acc = fdot2(R2[k][j].v2, WOu.v2[j], acc);
                dd[k] = acc;
            }
            // butterflies (select-free via k-permute)
            float xe = dpp_add<0xB1>(de[0], de[1]);
            float ye = dpp_add<0xB1>(de[2], de[3]);
            float De = dpp_add<0x4E>(xe, ye);
            De = dpp_add<0x104>(De, De);
            float xo = dpp_add<0xB1>(dd[0], dd[1]);
            float yo = dpp_add<0xB1>(dd[2], dd[3]);
            float Do = dpp_add<0x4E>(xo, yo);
            Do = dpp_add<0x104>(Do, Do);

            // softplus x2 (steps 2tt, 2tt+1)
            uint32 sg0 = bfe1(ows, 2 * tt) & 0x80000000u;
            float y0 = uas_f(fas_u(De) ^ sg0);
            float c0 = NHL2 * log2_n(1.f + exp2_n(LOG2E2 * y0));
            sum += uas_f(fas_u(c0) & bfe1(vmask, 2 * tt));
            uint32 sg1 = bfe1(ows, 2 * tt + 1) & 0x80000000u;
            float y1 = uas_f(fas_u(Do) ^ sg1);
            float c1 = NHL2 * log2_n(1.f + exp2_n(LOG2E2 * y1));
            sum += uas_f(fas_u(c1) & bfe1(vmask, 2 * tt + 1));

            // ONE update per pair: R *= 1 + cmb[combo]  (combo 00 row is 0)
            #pragma unroll
            for (int k = 0; k < 4; ++k) {
                U8 CMu;
                int cb = (p * 4 + (int)cbo[k]) * RST + s * 16;
                CMu.q4[0] = *(const uint4*)&cbuf[cb];
                CMu.q4[1] = *((const uint4*)&cbuf[cb] + 1);
                #pragma unroll
                for (int j = 0; j < 8; ++j)
                    R2[k][j].hh = __hfma2(CMu.hh[j], R2[k][j].hh, R2[k][j].hh);
            }
        }
    }
    if (s < 4) atomicAdd(&out[b0 + s], sum);
}

extern "C" void kernel_launch(void* const* d_in, const int* in_sizes, int n_in,
                              void* d_out, int out_size, void* d_ws, size_t ws_size,
                              hipStream_t stream) {
    const int*   inputs  = (const int*)d_in[0];     // (B, L) int32
    const float* epsilon = (const float*)d_in[1];   // (D, M, L) f32
    float* out = (float*)d_out;                     // (B,) f32

    char* ws = (char*)d_ws;
    _Float16* wE  = (_Float16*)(ws + OFF_WE);
    _Float16* wO  = (_Float16*)(ws + OFF_WO);
    _Float16* cmb = (_Float16*)(ws + OFF_CMB);
    unsigned short* lrT = (unsigned short*)(ws + OFF_LR);
    u64*   bits   = (u64*)  (ws + OFF_BITS);
    int*   T      = (int*)  (ws + OFF_T);
    _Float16* Rq  = (_Float16*)(ws + OFF_RQ);

    k_prep<<<PACK_BLK + EPS_BLK + ZERO_BLK, 256, 0, stream>>>(
        inputs, epsilon, bits, wE, wO, cmb, lrT, out);

    // CN=32 needs 64MB Rq; fall back to CN=16 if the workspace can't hold it.
    const size_t need32 = (size_t)OFF_RQ + (size_t)32 * B_N * M_N * 2;
    if (ws_size >= need32) {
        k_slog2<32><<<1024 + 32, 256, 0, stream>>>(bits, lrT, Rq, T);
        k_main<32><<<(B_N / 128) * 32, 256, 0, stream>>>(bits, wE, wO, cmb, Rq, T, out);
    } else {
        k_slog2<16><<<1024 + 32, 256, 0, stream>>>(bits, lrT, Rq, T);
        k_main<16><<<(B_N / 128) * 16, 256, 0, stream>>>(bits, wE, wO, cmb, Rq, T, out);
    }
}

// Round 12
// 162.472 us; speedup vs baseline: 1.1006x; 1.0056x over previous
//
#include <hip/hip_runtime.h>
#include <hip/hip_fp16.h>

typedef unsigned long long u64;
typedef unsigned int uint32;
typedef short short8 __attribute__((ext_vector_type(8)));
typedef float f32x4 __attribute__((ext_vector_type(4)));
typedef _Float16 h2 __attribute__((ext_vector_type(2)));

#define B_N 8192
#define L_N 1024
#define M_N 128
#define HALF_N 512

// ws layout (bytes)
#define OFF_WE   0x0         // wE[u][m] fp16, even-step weights: 128KB
#define OFF_CW   0x20000     // cw[u][4][256] fp16, [cmb|wO] super-rows: 1MB
#define OFF_LR   0x120000    // lrT[m][t] bf16: 256KB
#define OFF_BITS 0x160000    // bits[b][16] u64: 1MB
#define OFF_T    0x260000    // T[b] int32: 32KB
#define OFF_RQ   0x280000    // Rq[cn][b][m] fp16: 32MB (cn=16) or 64MB (cn=32)

#define PACK_BLK 2048
#define PACK_IT  16          // 2048*256*16 = B*L
#define EPS_BLK  32
#define ZERO_BLK 32

__device__ __forceinline__ unsigned short f32_bf16(float f) {
    union { float f; unsigned u; } x; x.f = f;
    unsigned u = x.u + 0x7FFFu + ((x.u >> 16) & 1u);   // RNE
    return (unsigned short)(u >> 16);
}

__device__ __forceinline__ float fdot2(h2 a, h2 b, float c) {
#if __has_builtin(__builtin_amdgcn_fdot2)
    return __builtin_amdgcn_fdot2(a, b, c, false);
#else
    return (float)a[0] * (float)b[0] + (float)a[1] * (float)b[1] + c;
#endif
}

__device__ __forceinline__ uint32 fas_u(float f) { union { float f; uint32 u; } x; x.f = f; return x.u; }
__device__ __forceinline__ float uas_f(uint32 u) { union { uint32 u; float f; } x; x.u = u; return x.f; }

__device__ __forceinline__ float exp2_n(float x) {
#if __has_builtin(__builtin_amdgcn_exp2f)
    return __builtin_amdgcn_exp2f(x);
#else
    return exp2f(x);
#endif
}
__device__ __forceinline__ float log2_n(float x) {
#if __has_builtin(__builtin_amdgcn_logf)
    return __builtin_amdgcn_logf(x);
#else
    return __log2f(x);
#endif
}
// sign-extended single-bit extract: 0 or 0xFFFFFFFF
__device__ __forceinline__ uint32 bfe1(uint32 v, int off) {
#if __has_builtin(__builtin_amdgcn_sbfe)
    return (uint32)__builtin_amdgcn_sbfe((int)v, off, 1);
#else
    return (uint32)((int)(v << (31 - off)) >> 31);
#endif
}
// unsigned 2-bit extract (the pair's combo index; bits are adjacent)
__device__ __forceinline__ uint32 ubfe2(uint32 v, int off) {
#if __has_builtin(__builtin_amdgcn_ubfe)
    return (uint32)__builtin_amdgcn_ubfe((int)v, off, 2);
#else
    return (v >> off) & 3u;
#endif
}

// x + dpp(y). CTRL: 0xB1 = quad_perm[1,0,3,2], 0x4E = quad_perm[2,3,0,1],
// 0x104 = row_shl:4 — all HW-proven in r3/r4/r5.
template<int CTRL>
__device__ __forceinline__ float dpp_add(float x, float y) {
    union { float f; int i; } a, r;
    a.f = y;
    r.i = __builtin_amdgcn_update_dpp(0, a.i, CTRL, 0xF, 0xF, true);
    return x + r.f;
}

union HU { uint32 u; __half2 hh; h2 v2; };

// ---- K0: fused prep: spin-pack | pair tables (fp16) | zero out ----------
__global__ __launch_bounds__(256) void k_prep(const int* __restrict__ inp,
        const float* __restrict__ eps, u64* __restrict__ bits,
        _Float16* __restrict__ wE, _Float16* __restrict__ cw,
        unsigned short* __restrict__ lrT, float* __restrict__ out) {
    int bid = blockIdx.x;
    if (bid < PACK_BLK) {
        int g = bid * 256 + threadIdx.x;
        const int stride = PACK_BLK * 256;
        #pragma unroll 4
        for (int it = 0; it < PACK_IT; ++it) {
            int v = inp[g];
            u64 m = __ballot(v != 0);
            if ((threadIdx.x & 63) == 0) bits[g >> 6] = m;
            g += stride;
        }
        return;
    }
    bid -= PACK_BLK;
    if (bid < EPS_BLK) {
        int wid = threadIdx.x >> 6, lane = threadIdx.x & 63;
        int m = bid * 4 + wid;
        const float* e0 = eps + (size_t)m * L_N + lane * 16;
        const float* e1 = eps + (size_t)(M_N + m) * L_N + lane * 16;
        float a[16], b[16];
        #pragma unroll
        for (int j = 0; j < 16; j += 4) {
            *(float4*)&a[j] = *(const float4*)&e0[j];
            *(float4*)&b[j] = *(const float4*)&e1[j];
        }
        float local = 1.f;
        #pragma unroll
        for (int j = 0; j < 16; ++j) local *= a[j];
        float sc = local;
        #pragma unroll
        for (int d = 1; d < 64; d <<= 1) {
            float up = __shfl_up(sc, d);
            if (lane >= d) sc *= up;
        }
        float prev = __shfl_up(sc, 1);
        float E = (lane == 0) ? 1.f : prev;
        int i0 = lane * 16;
        float rat_e = 1.f, w_e = 0.f;
        #pragma unroll
        for (int j = 0; j < 16; ++j) {
            float rat = b[j] / a[j];
            float w = E * (a[j] - b[j]);
            lrT[(size_t)m * L_N + i0 + j] = f32_bf16(__log2f(rat));
            int u = (i0 + j) >> 1;
            if ((j & 1) == 0) {
                wE[(size_t)u * M_N + m] = (_Float16)w;
                rat_e = rat;
            } else {
                // super-rows: [0..127]=cmb(combo) | [128..255]=wO(bit0=combo&1)
                _Float16* cr = cw + (size_t)u * 4 * 256;
                float wo1 = w * rat_e;
                cr[0 * 256 + m]       = (_Float16)0.f;
                cr[0 * 256 + 128 + m] = (_Float16)w;
                cr[1 * 256 + m]       = (_Float16)(rat_e - 1.f);
                cr[1 * 256 + 128 + m] = (_Float16)wo1;
                cr[2 * 256 + m]       = (_Float16)(rat - 1.f);
                cr[2 * 256 + 128 + m] = (_Float16)w;
                cr[3 * 256 + m]       = (_Float16)(rat_e * rat - 1.f);
                cr[3 * 256 + 128 + m] = (_Float16)wo1;
            }
            E *= a[j];
        }
        (void)w_e;
        return;
    }
    bid -= EPS_BLK;
    if (bid < ZERO_BLK) {
        out[bid * 256 + threadIdx.x] = 0.f;
    }
}

// ---- K2: MFMA chunk log-sums + f32 cumsum + exp2 -> fp16 excl prefix ----
// blocks [0,1024): prefix at CN granularity; [1024,1056): saturation T.
template<int CN>
__global__ __launch_bounds__(256) void k_slog2(const u64* __restrict__ bits,
        const unsigned short* __restrict__ lrT, _Float16* __restrict__ Rq,
        int* __restrict__ T) {
    if (blockIdx.x >= 1024) {
        int b = (blockIdx.x - 1024) * 256 + threadIdx.x;
        const u64* brow = bits + (size_t)b * 16;
        int n1 = 0, n0 = 0, Tv = 1024;
        for (int wd = 0; wd < 16; ++wd) {
            u64 x = brow[wd];
            int pc = __popcll(x);
            if (n1 + pc < HALF_N && n0 + (64 - pc) < HALF_N) {
                n1 += pc; n0 += 64 - pc;
                continue;
            }
            int found = 0;
            for (int k = 0; k < 64; ++k) {
                if (n1 >= HALF_N || n0 >= HALF_N) { Tv = wd * 64 + k; found = 1; break; }
                int sb = (int)((x >> k) & 1);
                n1 += sb; n0 += 1 - sb;
            }
            if (!found) Tv = (wd + 1) * 64;
            break;
        }
        T[b] = Tv;
        return;
    }
    int btile = blockIdx.x >> 1;
    int half = blockIdx.x & 1;
    int wid = threadIdx.x >> 6, lane = threadIdx.x & 63;
    int col = lane & 15, quad = lane >> 4;
    int m = (half * 4 + wid) * 16 + col;
    int b_row = btile * 16 + col;
    const u64* brow = bits + (size_t)b_row * 16;
    const unsigned short* lrow = lrT + (size_t)m * L_N;

    f32x4 cum = (f32x4){0.f, 0.f, 0.f, 0.f};

    for (int w = 0; w < 16; ++w) {
        u64 wv = brow[w];
        #pragma unroll
        for (int hf = 0; hf < 2; ++hf) {
            if (CN == 32 || hf == 0) {
                int cc = (CN == 32) ? (w * 2 + hf) : w;
                #pragma unroll
                for (int reg = 0; reg < 4; ++reg) {
                    int b = btile * 16 + quad * 4 + reg;
                    Rq[((size_t)cc * B_N + b) * M_N + m] = (_Float16)exp2_n(cum[reg]);
                }
            }
            short8 a;
            #pragma unroll
            for (int j = 0; j < 8; ++j)
                a[j] = (short)((((wv >> (hf * 32 + quad * 8 + j)) & 1) != 0) ? 0x3F80 : 0);
            union { uint4 u; short8 s; } bf;
            bf.u = *(const uint4*)(lrow + w * 64 + hf * 32 + quad * 8);
            cum = __builtin_amdgcn_mfma_f32_16x16x32_bf16(a, bf.s, cum, 0, 0, 0);
        }
    }
}

// ------- K3: main loop — pair-steps, combined [cmb|wO] super-row table ---
// Per pair tt: cbo = 2 spin bits. ONE address ad = tt*1024 + cbo*256 + s*16
// serves both the update row (cmb, at ad) and the odd-dot weight row (wO,
// at ad+128 — a ds_read immediate offset). Staging is per-32-step phase so
// the CN=16 fallback fits in 64KB LDS (CN=32 = single phase, == R10 flow).
template<int CN>
__global__ __launch_bounds__(256) __attribute__((amdgpu_waves_per_eu(1, 4)))
void k_main(const u64* __restrict__ bits, const _Float16* __restrict__ wE,
        const _Float16* __restrict__ cw, const _Float16* __restrict__ Rq,
        const int* __restrict__ T, float* __restrict__ out) {
    constexpr int CHN = L_N / CN;                // 64 or 32 steps per chunk
    constexpr int CSH = (CN == 16) ? 4 : 5;
    __shared__ _Float16 webuf[16 * M_N];         // 4KB  (16 pairs/phase)
    __shared__ _Float16 cwbuf[16 * 4 * 256];     // 32KB
    int c = blockIdx.x & (CN - 1);
    int bblk = blockIdx.x >> CSH;
    int lane = threadIdx.x & 63, wid = threadIdx.x >> 6;
    int s = lane & 7, grp = lane >> 3;
    int q = s & 3;
    int b0 = bblk * 128 + wid * 32 + grp * 4;

    // prefix load: R2[k][j] = packed pair for b0+(q^k), m = s*16+2j
    HU R2[4][8];
    u64 wb[4];
    const int word0 = (c * CHN) >> 6;            // u64 word holding this chunk
    const int hs0 = ((c * CHN) >> 5) & 1;        // starting 32-bit half
    #pragma unroll
    for (int k = 0; k < 4; ++k) {
        int b = b0 + (q ^ k);
        union { uint4 v[2]; uint32 w[8]; } P;
        const uint4* src = (const uint4*)(Rq + ((size_t)c * B_N + b) * M_N + s * 16);
        P.v[0] = src[0]; P.v[1] = src[1];
        #pragma unroll
        for (int j = 0; j < 8; ++j) R2[k][j].u = P.w[j];
        wb[k] = bits[(size_t)b * 16 + word0];
    }
    int Tb = T[b0 + q];

    const float LOG2E2 = 2.885390082f; // 2*log2(e)
    const float NHL2 = -0.3465735903f; // -0.5*ln2
    float sum = 0.f;
    #pragma unroll
    for (int h = 0; h < CHN / 32; ++h) {
        // stage phase h: 16 pairs (coalesced uint4, linear layout)
        if (h) __syncthreads();
        {
            size_t pbase = (size_t)c * (CHN / 2) + h * 16;
            const uint4* se = (const uint4*)(wE + pbase * M_N);
            const uint4* sc = (const uint4*)(cw + pbase * 4 * 256);
            ((uint4*)webuf)[threadIdx.x] = se[threadIdx.x];
            #pragma unroll
            for (int t = 0; t < 8; ++t)
                ((uint4*)cwbuf)[threadIdx.x + t * 256] = sc[threadIdx.x + t * 256];
        }
        __syncthreads();

        int sh = ((hs0 + h) & 1) * 32;
        uint32 wh[4];
        #pragma unroll
        for (int k = 0; k < 4; ++k) wh[k] = (uint32)(wb[k] >> sh);
        uint32 ows = ~wh[0];                   // own b's word; bit==0 -> flip sign
        int rel = Tb - (c * CHN + h * 32);
        uint32 vmask = (rel <= 0) ? 0u : ((rel >= 32) ? 0xFFFFFFFFu : ((1u << rel) - 1u));

        #pragma unroll 2
        for (int tt = 0; tt < 16; ++tt) {      // 16 pairs = 32 steps
            union U8 { uint4 q4[2]; uint32 w[8]; h2 v2[8]; __half2 hh[8]; };
            U8 WEu;
            const _Float16* web = &webuf[tt * M_N + s * 16];
            WEu.q4[0] = *(const uint4*)web;
            WEu.q4[1] = *((const uint4*)web + 1);

            int pb = tt * 1024 + s * 16;
            int ad[4];
            #pragma unroll
            for (int k = 0; k < 4; ++k)
                ad[k] = pb + (int)(ubfe2(wh[k], 2 * tt) << 8);

            // even dots: shared wE
            float de[4];
            #pragma unroll
            for (int k = 0; k < 4; ++k) {
                float acc = 0.f;
                #pragma unroll
                for (int j = 0; j < 8; ++j) acc = fdot2(R2[k][j].v2, WEu.v2[j], acc);
                de[k] = acc;
            }
            // odd dots: wO half of the selected super-row (+128 elem imm)
            float dd[4];
            #pragma unroll
            for (int k = 0; k < 4; ++k) {
                U8 WOu;
                WOu.q4[0] = *(const uint4*)&cwbuf[ad[k] + 128];
                WOu.q4[1] = *((const uint4*)&cwbuf[ad[k] + 128] + 1);
                float acc = 0.f;
                #pragma unroll
                for (int j = 0; j < 8; ++j) acc = fdot2(R2[k][j].v2, WOu.v2[j], acc);
                dd[k] = acc;
            }
            // butterflies (select-free via k-permute)
            float xe = dpp_add<0xB1>(de[0], de[1]);
            float ye = dpp_add<0xB1>(de[2], de[3]);
            float De = dpp_add<0x4E>(xe, ye);
            De = dpp_add<0x104>(De, De);
            float xo = dpp_add<0xB1>(dd[0], dd[1]);
            float yo = dpp_add<0xB1>(dd[2], dd[3]);
            float Do = dpp_add<0x4E>(xo, yo);
            Do = dpp_add<0x104>(Do, Do);

            // softplus x2 (steps 2tt, 2tt+1), fma-folded tail
            uint32 sg0 = bfe1(ows, 2 * tt) & 0x80000000u;
            float l0 = log2_n(1.f + exp2_n(LOG2E2 * uas_f(fas_u(De) ^ sg0)));
            sum = fmaf(NHL2, uas_f(fas_u(l0) & bfe1(vmask, 2 * tt)), sum);
            uint32 sg1 = bfe1(ows, 2 * tt + 1) & 0x80000000u;
            float l1 = log2_n(1.f + exp2_n(LOG2E2 * uas_f(fas_u(Do) ^ sg1)));
            sum = fmaf(NHL2, uas_f(fas_u(l1) & bfe1(vmask, 2 * tt + 1)), sum);

            // ONE update per pair: R *= 1 + cmb[combo] (cmb half, at ad)
            #pragma unroll
            for (int k = 0; k < 4; ++k) {
                U8 CMu;
                CMu.q4[0] = *(const uint4*)&cwbuf[ad[k]];
                CMu.q4[1] = *((const uint4*)&cwbuf[ad[k]] + 1);
                #pragma unroll
                for (int j = 0; j < 8; ++j)
                    R2[k][j].hh = __hfma2(CMu.hh[j], R2[k][j].hh, R2[k][j].hh);
            }
        }
    }
    if (s < 4) atomicAdd(&out[b0 + s], sum);
}

extern "C" void kernel_launch(void* const* d_in, const int* in_sizes, int n_in,
                              void* d_out, int out_size, void* d_ws, size_t ws_size,
                              hipStream_t stream) {
    const int*   inputs  = (const int*)d_in[0];     // (B, L) int32
    const float* epsilon = (const float*)d_in[1];   // (D, M, L) f32
    float* out = (float*)d_out;                     // (B,) f32

    char* ws = (char*)d_ws;
    _Float16* wE  = (_Float16*)(ws + OFF_WE);
    _Float16* cw  = (_Float16*)(ws + OFF_CW);
    unsigned short* lrT = (unsigned short*)(ws + OFF_LR);
    u64*   bits   = (u64*)  (ws + OFF_BITS);
    int*   T      = (int*)  (ws + OFF_T);
    _Float16* Rq  = (_Float16*)(ws + OFF_RQ);

    k_prep<<<PACK_BLK + EPS_BLK + ZERO_BLK, 256, 0, stream>>>(
        inputs, epsilon, bits, wE, cw, lrT, out);

    // CN=32 needs 64MB Rq; fall back to CN=16 if the workspace can't hold it.
    const size_t need32 = (size_t)OFF_RQ + (size_t)32 * B_N * M_N * 2;
    if (ws_size >= need32) {
        k_slog2<32><<<1024 + 32, 256, 0, stream>>>(bits, lrT, Rq, T);
        k_main<32><<<(B_N / 128) * 32, 256, 0, stream>>>(bits, wE, cw, Rq, T, out);
    } else {
        k_slog2<16><<<1024 + 32, 256, 0, stream>>>(bits, lrT, Rq, T);
        k_main<16><<<(B_N / 128) * 16, 256, 0, stream>>>(bits, wE, cw, Rq, T, out);
    }
}